// Round 1
// baseline (1181.417 us; speedup 1.0000x reference)
//
#include <hip/hip_runtime.h>
#include <hip/hip_bf16.h>
#include <math.h>

typedef __bf16 bf16;
typedef __bf16 bf16x8 __attribute__((ext_vector_type(8)));
typedef float f32x4 __attribute__((ext_vector_type(4)));

#define HS 2048
#define NH 16
#define HD 128
#define LT 512
#define LI 2048
#define LQ 2560
#define MLP_D 8192

__device__ __forceinline__ f32x4 mfma16(bf16x8 a, bf16x8 b, f32x4 c) {
  return __builtin_amdgcn_mfma_f32_16x16x32_bf16(a, b, c, 0, 0, 0);
}

// ---------------- silu(vec) ----------------
__global__ void k_silu(const float* __restrict__ v, float* __restrict__ s) {
  int i = blockIdx.x * 256 + threadIdx.x;
  float x = v[i];
  s[i] = x / (1.f + expf(-x));
}

// ---------------- mod GEMV: silu(vec) @ mod_w, 2-pass (deterministic) ----------------
// grid (96, 8): blockIdx.x: strm = x/48 (0=txt,1=img), n0=(x%48)*256 ; blockIdx.y = k-chunk
__global__ __launch_bounds__(256) void k_mod_partial(
    const float* __restrict__ s, const float* __restrict__ w_txt,
    const float* __restrict__ w_img, float* __restrict__ part) {
  int strm = blockIdx.x / 48;
  int n = (blockIdx.x % 48) * 256 + threadIdx.x;
  const float* w = strm ? w_img : w_txt;
  int k0 = blockIdx.y * 256;
  __shared__ float sl[256];
  sl[threadIdx.x] = s[k0 + threadIdx.x];
  __syncthreads();
  float acc = 0.f;
  for (int k = 0; k < 256; k++)
    acc += sl[k] * w[(size_t)(k0 + k) * 12288 + n];
  part[((size_t)blockIdx.y * 2 + strm) * 12288 + n] = acc;
}

__global__ __launch_bounds__(256) void k_mod_reduce(
    const float* __restrict__ part, const float* __restrict__ b_txt,
    const float* __restrict__ b_img, float* __restrict__ mod) {
  int strm = blockIdx.x / 48;
  int n = (blockIdx.x % 48) * 256 + threadIdx.x;
  float acc = strm ? b_img[n] : b_txt[n];
  for (int kc = 0; kc < 8; kc++)
    acc += part[((size_t)kc * 2 + strm) * 12288 + n];
  mod[(size_t)strm * 12288 + n] = acc;
}

// ---------------- weight transpose + fp32->bf16 : src[R][C] -> dst[C][R] ----------------
__global__ __launch_bounds__(256) void k_transpose_cvt(
    const float* __restrict__ src, bf16* __restrict__ dst, int R, int C) {
  __shared__ float t[32][33];
  int tx = threadIdx.x & 31, ty = threadIdx.x >> 5;
  int c0 = blockIdx.x * 32, r0 = blockIdx.y * 32;
  for (int i = 0; i < 32; i += 8)
    t[ty + i][tx] = src[(size_t)(r0 + ty + i) * C + c0 + tx];
  __syncthreads();
  for (int i = 0; i < 32; i += 8)
    dst[(size_t)(c0 + ty + i) * R + r0 + tx] = (bf16)t[tx][ty + i];
}

// ---------------- LayerNorm + modulate -> bf16 ----------------
// row r: r<512 -> stream0 (txt, x0 local rows), else stream1 (img)
__global__ __launch_bounds__(256) void k_ln_mod(
    const float* __restrict__ x0, const float* __restrict__ x1,
    const float* __restrict__ ls0, const float* __restrict__ lb0,
    const float* __restrict__ ls1, const float* __restrict__ lb1,
    const float* __restrict__ mod0, const float* __restrict__ mod1,
    int shidx, int scidx, bf16* __restrict__ out) {
  int r = blockIdx.x;
  int strm = r >= LT;
  const float* x = strm ? (x1 + (size_t)(r - LT) * HS) : (x0 + (size_t)r * HS);
  const float* ls = strm ? ls1 : ls0;
  const float* lb = strm ? lb1 : lb0;
  const float* md = strm ? mod1 : mod0;
  const float* sh = md + (size_t)shidx * HS;
  const float* sc = md + (size_t)scidx * HS;
  int t = threadIdx.x;
  float4 a = ((const float4*)x)[t * 2];
  float4 b = ((const float4*)x)[t * 2 + 1];
  float xv[8] = {a.x, a.y, a.z, a.w, b.x, b.y, b.z, b.w};
  float sum = 0.f, sq = 0.f;
#pragma unroll
  for (int j = 0; j < 8; j++) { sum += xv[j]; sq += xv[j] * xv[j]; }
#pragma unroll
  for (int m = 32; m; m >>= 1) { sum += __shfl_xor(sum, m); sq += __shfl_xor(sq, m); }
  __shared__ float red[8];
  int lane = t & 63, wid = t >> 6;
  if (!lane) { red[wid] = sum; red[wid + 4] = sq; }
  __syncthreads();
  float ts = red[0] + red[1] + red[2] + red[3];
  float tq = red[4] + red[5] + red[6] + red[7];
  float mean = ts * (1.f / HS);
  float var = tq * (1.f / HS) - mean * mean;
  float inv = rsqrtf(var + 1e-6f);
  int c0 = t * 8;
  bf16x8 ov;
#pragma unroll
  for (int j = 0; j < 8; j++) {
    int c = c0 + j;
    float v = ((xv[j] - mean) * inv * ls[c] + lb[c]) * (1.f + sc[c]) + sh[c];
    ov[j] = (bf16)v;
  }
  *(bf16x8*)(out + (size_t)r * HS + c0) = ov;
}

// ---------------- GEMM: A[2560][K] bf16 @ BT[N][K] bf16, dual-stream weights ----------------
// MODE 0: out bf16 = acc+bias     (qkv)
// MODE 1: out f32  = res + gate*(acc+bias)   (proj, residual)
// MODE 2: out bf16 = gelu_tanh(acc+bias)     (mlp1)
// MODE 3: out f32  = res + gate*(acc+bias)   (mlp2 -> d_out)
template <int MODE>
__global__ __launch_bounds__(256) void k_gemm(
    const bf16* __restrict__ A, int K, int N,
    const bf16* __restrict__ BT0, const bf16* __restrict__ BT1,
    const float* __restrict__ bias0, const float* __restrict__ bias1,
    const float* __restrict__ gate0, const float* __restrict__ gate1,
    const float* __restrict__ res0, const float* __restrict__ res1,
    void* __restrict__ out0, void* __restrict__ out1) {
  __shared__ bf16 As[128 * 32];
  __shared__ bf16 Bs[128 * 32];
  int tid = threadIdx.x;
  int bn = blockIdx.x, bm = blockIdx.y;
  int strm = (bm * 128) >= LT;
  int lm = bm * 128 - strm * LT;  // local row base within stream
  const bf16* BT = strm ? BT1 : BT0;
  const float* bias = strm ? bias1 : bias0;
  int lane = tid & 63, wid = tid >> 6;
  int wr = wid >> 1, wc = wid & 1;
  int sr = tid >> 2, sc8 = (tid & 3) * 8;
  const bf16* Ag = A + (size_t)(bm * 128 + sr) * K + sc8;
  const bf16* Bg = BT + (size_t)(bn * 128 + sr) * K + sc8;
  f32x4 acc[4][4] = {};
  for (int k0 = 0; k0 < K; k0 += 32) {
    __syncthreads();
    *(bf16x8*)&As[sr * 32 + sc8] = *(const bf16x8*)(Ag + k0);
    *(bf16x8*)&As[(sr + 64) * 32 + sc8] = *(const bf16x8*)(Ag + (size_t)64 * K + k0);
    *(bf16x8*)&Bs[sr * 32 + sc8] = *(const bf16x8*)(Bg + k0);
    *(bf16x8*)&Bs[(sr + 64) * 32 + sc8] = *(const bf16x8*)(Bg + (size_t)64 * K + k0);
    __syncthreads();
    bf16x8 af[4], bfr[4];
    int r16 = lane & 15, kc8 = (lane >> 4) * 8;
#pragma unroll
    for (int m = 0; m < 4; m++) af[m] = *(const bf16x8*)&As[(wr * 64 + m * 16 + r16) * 32 + kc8];
#pragma unroll
    for (int n = 0; n < 4; n++) bfr[n] = *(const bf16x8*)&Bs[(wc * 64 + n * 16 + r16) * 32 + kc8];
#pragma unroll
    for (int m = 0; m < 4; m++)
#pragma unroll
      for (int n = 0; n < 4; n++)
        acc[m][n] = mfma16(af[m], bfr[n], acc[m][n]);
  }
  int col = lane & 15, rb = (lane >> 4) * 4;
#pragma unroll
  for (int m = 0; m < 4; m++) {
#pragma unroll
    for (int n = 0; n < 4; n++) {
      int gn = bn * 128 + wc * 64 + n * 16 + col;
      float bv = bias[gn];
#pragma unroll
      for (int r = 0; r < 4; r++) {
        int gr = lm + wr * 64 + m * 16 + rb + r;
        size_t oi = (size_t)gr * N + gn;
        float v = acc[m][n][r] + bv;
        if (MODE == 0) {
          ((bf16*)(strm ? out1 : out0))[oi] = (bf16)v;
        } else if (MODE == 2) {
          float g = 0.5f * v * (1.f + tanhf(0.7978845608028654f * (v + 0.044715f * v * v * v)));
          ((bf16*)(strm ? out1 : out0))[oi] = (bf16)g;
        } else {
          const float* gate = strm ? gate1 : gate0;
          const float* res = strm ? res1 : res0;
          float o = res[oi] + gate[gn] * v;
          ((float*)(strm ? out1 : out0))[oi] = o;
        }
      }
    }
  }
}

// ---------------- qkv post: RMS norm (q,k) + RoPE + scale, v transpose ----------------
// one wave per (head, l); lane owns pair d = lane (elems 2*lane, 2*lane+1)
__global__ __launch_bounds__(256) void k_qkv_post(
    const bf16* __restrict__ y, const float* __restrict__ pe,
    const float* __restrict__ qn0, const float* __restrict__ kn0,
    const float* __restrict__ qn1, const float* __restrict__ kn1,
    bf16* __restrict__ qh, bf16* __restrict__ kh, bf16* __restrict__ vT) {
  int wv = (int)((blockIdx.x * 256 + threadIdx.x) >> 6);
  int lane = threadIdx.x & 63;
  int head = wv / LQ, l = wv - head * LQ;
  const bf16* yr = y + (size_t)l * (3 * HS) + head * HD;
  float q0 = (float)yr[2 * lane], q1 = (float)yr[2 * lane + 1];
  float k0 = (float)yr[HS + 2 * lane], k1 = (float)yr[HS + 2 * lane + 1];
  float v0 = (float)yr[2 * HS + 2 * lane], v1 = (float)yr[2 * HS + 2 * lane + 1];
  float sqs = q0 * q0 + q1 * q1, sks = k0 * k0 + k1 * k1;
#pragma unroll
  for (int m = 1; m < 64; m <<= 1) { sqs += __shfl_xor(sqs, m); sks += __shfl_xor(sks, m); }
  float rq = rsqrtf(sqs * (1.f / HD) + 1e-6f);
  float rk = rsqrtf(sks * (1.f / HD) + 1e-6f);
  int strm = l >= LT;
  const float* qn = strm ? qn1 : qn0;
  const float* kn = strm ? kn1 : kn0;
  float e0 = q0 * rq * qn[2 * lane], e1 = q1 * rq * qn[2 * lane + 1];
  float f0 = k0 * rk * kn[2 * lane], f1 = k1 * rk * kn[2 * lane + 1];
  float4 p = *(const float4*)(pe + ((size_t)l * 64 + lane) * 4);
  const float scl = 0.08838834764831845f;  // 128^-0.5 folded into q
  float oq0 = (p.x * e0 + p.y * e1) * scl, oq1 = (p.z * e0 + p.w * e1) * scl;
  float ok0 = p.x * f0 + p.y * f1, ok1 = p.z * f0 + p.w * f1;
  size_t qi = ((size_t)head * LQ + l) * HD + 2 * lane;
  qh[qi] = (bf16)oq0; qh[qi + 1] = (bf16)oq1;
  kh[qi] = (bf16)ok0; kh[qi + 1] = (bf16)ok1;
  size_t vi = ((size_t)head * HD + 2 * lane) * LQ + l;
  vT[vi] = (bf16)v0; vT[vi + LQ] = (bf16)v1;
}

// ---------------- flash attention ----------------
// block = 4 waves; wave handles 16 q rows of one head; KV tile = 32
__global__ __launch_bounds__(256) void k_attn(
    const bf16* __restrict__ Q, const bf16* __restrict__ Kh,
    const bf16* __restrict__ VT, bf16* __restrict__ out) {
  __shared__ bf16 P[4][16 * 40];  // per-wave [16 rows][40 (32 used, pad to 40)]
  int tid = threadIdx.x, lane = tid & 63, w = tid >> 6;
  int head = blockIdx.x / 40, qb = blockIdx.x % 40;
  int qr = qb * 64 + w * 16;
  int r16 = lane & 15, kc = lane >> 4;  // kc in 0..3
  const bf16* qp = Q + ((size_t)head * LQ + qr + r16) * HD + kc * 8;
  bf16x8 qf[4];
#pragma unroll
  for (int c = 0; c < 4; c++) qf[c] = *(const bf16x8*)(qp + c * 32);
  f32x4 O[8] = {};
  float mr[4], lr[4];
#pragma unroll
  for (int i = 0; i < 4; i++) { mr[i] = -1e30f; lr[i] = 0.f; }
  bf16* pl = &P[w][0];
  const bf16* kbase = Kh + (size_t)head * LQ * HD;
  const bf16* vbase = VT + (size_t)head * HD * LQ;
  for (int t = 0; t < LQ / 32; t++) {
    const bf16* kp = kbase + (size_t)(t * 32 + r16) * HD + kc * 8;
    f32x4 S0 = {}, S1 = {};
#pragma unroll
    for (int c = 0; c < 4; c++) {
      bf16x8 ka = *(const bf16x8*)(kp + c * 32);
      bf16x8 kb = *(const bf16x8*)(kp + 16 * HD + c * 32);
      S0 = mfma16(qf[c], ka, S0);
      S1 = mfma16(qf[c], kb, S1);
    }
    float alpha[4];
#pragma unroll
    for (int i = 0; i < 4; i++) {
      float mx = fmaxf(S0[i], S1[i]);
#pragma unroll
      for (int m = 8; m; m >>= 1) mx = fmaxf(mx, __shfl_xor(mx, m));
      float mn = fmaxf(mr[i], mx);
      float p0 = __expf(S0[i] - mn), p1 = __expf(S1[i] - mn);
      float rs = p0 + p1;
#pragma unroll
      for (int m = 8; m; m >>= 1) rs += __shfl_xor(rs, m);
      alpha[i] = __expf(mr[i] - mn);
      lr[i] = lr[i] * alpha[i] + rs;
      mr[i] = mn;
      pl[(4 * kc + i) * 40 + r16] = (bf16)p0;         // D layout: row=4*kc+i, col=r16
      pl[(4 * kc + i) * 40 + 16 + r16] = (bf16)p1;    // second 16-col half
    }
    __syncthreads();  // drain LDS writes (per-wave buffer; barrier gives lgkmcnt(0))
    bf16x8 pf = *(const bf16x8*)&pl[r16 * 40 + kc * 8];  // A-frag: row=r16, kv=kc*8..+7
    const bf16* vp = vbase + (size_t)r16 * LQ + t * 32 + kc * 8;
#pragma unroll
    for (int n = 0; n < 8; n++) {
      bf16x8 vf = *(const bf16x8*)(vp + (size_t)n * 16 * LQ);
      f32x4 o = O[n];
#pragma unroll
      for (int i = 0; i < 4; i++) o[i] *= alpha[i];
      O[n] = mfma16(pf, vf, o);
    }
    __syncthreads();
  }
#pragma unroll
  for (int n = 0; n < 8; n++)
#pragma unroll
    for (int i = 0; i < 4; i++) {
      float v = O[n][i] / lr[i];
      out[(size_t)(qr + 4 * kc + i) * HS + head * HD + n * 16 + r16] = (bf16)v;
    }
}

// ---------------- launch ----------------
extern "C" void kernel_launch(void* const* d_in, const int* in_sizes, int n_in,
                              void* d_out, int out_size, void* d_ws, size_t ws_size,
                              hipStream_t stream) {
  const float* img = (const float*)d_in[0];
  const float* txt = (const float*)d_in[1];
  const float* vec = (const float*)d_in[2];
  const float* pe = (const float*)d_in[3];
#define PARAM(i) ((const float*)d_in[i])
  // img params 4..19, txt params 20..35

  char* ws = (char*)d_ws;
  size_t off = 0;
  auto alloc = [&](size_t b) { void* p = ws + off; off += (b + 255) & ~(size_t)255; return p; };
  float* silu_s = (float*)alloc((size_t)HS * 4);
  float* mpart = (float*)alloc((size_t)8 * 2 * 12288 * 4);
  float* mod = (float*)alloc((size_t)2 * 6 * HS * 4);  // [strm][6][2048], strm0=txt
  bf16* qkvT0 = (bf16*)alloc((size_t)3 * HS * HS * 2);
  bf16* qkvT1 = (bf16*)alloc((size_t)3 * HS * HS * 2);
  bf16* projT0 = (bf16*)alloc((size_t)HS * HS * 2);
  bf16* projT1 = (bf16*)alloc((size_t)HS * HS * 2);
  bf16* mlp1T0 = (bf16*)alloc((size_t)MLP_D * HS * 2);
  bf16* mlp1T1 = (bf16*)alloc((size_t)MLP_D * HS * 2);
  bf16* mlp2T0 = (bf16*)alloc((size_t)HS * MLP_D * 2);
  bf16* mlp2T1 = (bf16*)alloc((size_t)HS * MLP_D * 2);
  bf16* xm = (bf16*)alloc((size_t)LQ * HS * 2);
  bf16* y = (bf16*)alloc((size_t)LQ * 3 * HS * 2);
  bf16* qh = (bf16*)alloc((size_t)NH * LQ * HD * 2);
  bf16* kh = (bf16*)alloc((size_t)NH * LQ * HD * 2);
  bf16* vT = (bf16*)alloc((size_t)NH * HD * LQ * 2);
  bf16* attnb = (bf16*)alloc((size_t)LQ * HS * 2);
  float* x2 = (float*)alloc((size_t)LQ * HS * 4);
  bf16* xm2 = (bf16*)alloc((size_t)LQ * HS * 2);
  bf16* h = (bf16*)alloc((size_t)LQ * MLP_D * 2);
  (void)ws_size; (void)in_sizes; (void)n_in; (void)out_size;

  const float* t_mod = mod;                 // txt mod vectors [6][2048]
  const float* i_mod = mod + 6 * HS;        // img

  // 1) modulation vectors
  k_silu<<<HS / 256, 256, 0, stream>>>(vec, silu_s);
  k_mod_partial<<<dim3(96, 8), 256, 0, stream>>>(silu_s, PARAM(20), PARAM(4), mpart);
  k_mod_reduce<<<96, 256, 0, stream>>>(mpart, PARAM(21), PARAM(5), mod);

  // 2) weight transpose+cvt (dst[C][R] bf16)
  k_transpose_cvt<<<dim3(3 * HS / 32, HS / 32), 256, 0, stream>>>(PARAM(24), qkvT0, HS, 3 * HS);
  k_transpose_cvt<<<dim3(3 * HS / 32, HS / 32), 256, 0, stream>>>(PARAM(8), qkvT1, HS, 3 * HS);
  k_transpose_cvt<<<dim3(HS / 32, HS / 32), 256, 0, stream>>>(PARAM(28), projT0, HS, HS);
  k_transpose_cvt<<<dim3(HS / 32, HS / 32), 256, 0, stream>>>(PARAM(12), projT1, HS, HS);
  k_transpose_cvt<<<dim3(MLP_D / 32, HS / 32), 256, 0, stream>>>(PARAM(32), mlp1T0, HS, MLP_D);
  k_transpose_cvt<<<dim3(MLP_D / 32, HS / 32), 256, 0, stream>>>(PARAM(16), mlp1T1, HS, MLP_D);
  k_transpose_cvt<<<dim3(HS / 32, MLP_D / 32), 256, 0, stream>>>(PARAM(34), mlp2T0, MLP_D, HS);
  k_transpose_cvt<<<dim3(HS / 32, MLP_D / 32), 256, 0, stream>>>(PARAM(18), mlp2T1, MLP_D, HS);

  // 3) LN1 + modulate -> xm (bf16, txt rows first)
  k_ln_mod<<<LQ, 256, 0, stream>>>(txt, img, PARAM(22), PARAM(23), PARAM(6), PARAM(7),
                                   t_mod, i_mod, 0, 1, xm);

  // 4) qkv GEMM -> y [2560][6144] bf16
  k_gemm<0><<<dim3(3 * HS / 128, LQ / 128), 256, 0, stream>>>(
      xm, HS, 3 * HS, qkvT0, qkvT1, PARAM(25), PARAM(9),
      nullptr, nullptr, nullptr, nullptr, y, y + (size_t)LT * 3 * HS);

  // 5) RMS + RoPE + scale -> qh, kh; V transpose -> vT
  k_qkv_post<<<NH * LQ / 4, 256, 0, stream>>>(y, pe, PARAM(26), PARAM(27), PARAM(10), PARAM(11),
                                              qh, kh, vT);

  // 6) attention -> attnb [2560][2048] bf16
  k_attn<<<NH * (LQ / 64), 256, 0, stream>>>(qh, kh, vT, attnb);

  // 7) proj GEMM + gated residual -> x2 (f32)
  k_gemm<1><<<dim3(HS / 128, LQ / 128), 256, 0, stream>>>(
      attnb, HS, HS, projT0, projT1, PARAM(29), PARAM(13),
      t_mod + 2 * HS, i_mod + 2 * HS, txt, img, x2, x2 + (size_t)LT * HS);

  // 8) LN2 + modulate -> xm2
  k_ln_mod<<<LQ, 256, 0, stream>>>(x2, x2 + (size_t)LT * HS, PARAM(30), PARAM(31), PARAM(14),
                                   PARAM(15), t_mod, i_mod, 3, 4, xm2);

  // 9) MLP1 + gelu -> h bf16
  k_gemm<2><<<dim3(MLP_D / 128, LQ / 128), 256, 0, stream>>>(
      xm2, HS, MLP_D, mlp1T0, mlp1T1, PARAM(33), PARAM(17),
      nullptr, nullptr, nullptr, nullptr, h, h + (size_t)LT * MLP_D);

  // 10) MLP2 + gated residual -> d_out (img first, then txt)
  float* out_img = (float*)d_out;
  float* out_txt = (float*)d_out + (size_t)LI * HS;
  k_gemm<3><<<dim3(HS / 128, LQ / 128), 256, 0, stream>>>(
      h, MLP_D, HS, mlp2T0, mlp2T1, PARAM(35), PARAM(19),
      t_mod + 5 * HS, i_mod + 5 * HS, x2, x2 + (size_t)LT * HS, out_txt, out_img);
}

// Round 2
// 1146.026 us; speedup vs baseline: 1.0309x; 1.0309x over previous
//
#include <hip/hip_runtime.h>
#include <hip/hip_bf16.h>
#include <math.h>

typedef __bf16 bf16;
typedef __bf16 bf16x2 __attribute__((ext_vector_type(2)));
typedef __bf16 bf16x8 __attribute__((ext_vector_type(8)));
typedef float f32x4 __attribute__((ext_vector_type(4)));

#define HS 2048
#define NH 16
#define HD 128
#define LT 512
#define LI 2048
#define LQ 2560
#define MLP_D 8192

__device__ __forceinline__ f32x4 mfma16(bf16x8 a, bf16x8 b, f32x4 c) {
  return __builtin_amdgcn_mfma_f32_16x16x32_bf16(a, b, c, 0, 0, 0);
}

// async global->LDS, 16B per lane; lds dest must be wave-uniform base (+lane*16 by HW)
__device__ __forceinline__ void gl_lds16(const bf16* g, bf16* l) {
  __builtin_amdgcn_global_load_lds((const __attribute__((address_space(1))) void*)g,
                                   (__attribute__((address_space(3))) void*)l, 16, 0, 0);
}

// ---------------- silu(vec) ----------------
__global__ void k_silu(const float* __restrict__ v, float* __restrict__ s) {
  int i = blockIdx.x * 256 + threadIdx.x;
  float x = v[i];
  s[i] = x / (1.f + expf(-x));
}

// ---------------- mod GEMV: silu(vec) @ mod_w, 2-pass (deterministic) ----------------
__global__ __launch_bounds__(256) void k_mod_partial(
    const float* __restrict__ s, const float* __restrict__ w_txt,
    const float* __restrict__ w_img, float* __restrict__ part) {
  int strm = blockIdx.x / 48;
  int n = (blockIdx.x % 48) * 256 + threadIdx.x;
  const float* w = strm ? w_img : w_txt;
  int k0 = blockIdx.y * 256;
  __shared__ float sl[256];
  sl[threadIdx.x] = s[k0 + threadIdx.x];
  __syncthreads();
  float acc = 0.f;
  for (int k = 0; k < 256; k++)
    acc += sl[k] * w[(size_t)(k0 + k) * 12288 + n];
  part[((size_t)blockIdx.y * 2 + strm) * 12288 + n] = acc;
}

__global__ __launch_bounds__(256) void k_mod_reduce(
    const float* __restrict__ part, const float* __restrict__ b_txt,
    const float* __restrict__ b_img, float* __restrict__ mod) {
  int strm = blockIdx.x / 48;
  int n = (blockIdx.x % 48) * 256 + threadIdx.x;
  float acc = strm ? b_img[n] : b_txt[n];
  for (int kc = 0; kc < 8; kc++)
    acc += part[((size_t)kc * 2 + strm) * 12288 + n];
  mod[(size_t)strm * 12288 + n] = acc;
}

// ---------------- weight transpose + fp32->bf16 : src[R][C] -> dst[C][R] ----------------
__global__ __launch_bounds__(256) void k_transpose_cvt(
    const float* __restrict__ src, bf16* __restrict__ dst, int R, int C) {
  __shared__ float t[32][33];
  int tx = threadIdx.x & 31, ty = threadIdx.x >> 5;
  int c0 = blockIdx.x * 32, r0 = blockIdx.y * 32;
  for (int i = 0; i < 32; i += 8)
    t[ty + i][tx] = src[(size_t)(r0 + ty + i) * C + c0 + tx];
  __syncthreads();
  for (int i = 0; i < 32; i += 8)
    dst[(size_t)(c0 + ty + i) * R + r0 + tx] = (bf16)t[tx][ty + i];
}

// ---------------- LayerNorm + modulate -> bf16 ----------------
__global__ __launch_bounds__(256) void k_ln_mod(
    const float* __restrict__ x0, const float* __restrict__ x1,
    const float* __restrict__ ls0, const float* __restrict__ lb0,
    const float* __restrict__ ls1, const float* __restrict__ lb1,
    const float* __restrict__ mod0, const float* __restrict__ mod1,
    int shidx, int scidx, bf16* __restrict__ out) {
  int r = blockIdx.x;
  int strm = r >= LT;
  const float* x = strm ? (x1 + (size_t)(r - LT) * HS) : (x0 + (size_t)r * HS);
  const float* ls = strm ? ls1 : ls0;
  const float* lb = strm ? lb1 : lb0;
  const float* md = strm ? mod1 : mod0;
  const float* sh = md + (size_t)shidx * HS;
  const float* sc = md + (size_t)scidx * HS;
  int t = threadIdx.x;
  float4 a = ((const float4*)x)[t * 2];
  float4 b = ((const float4*)x)[t * 2 + 1];
  float xv[8] = {a.x, a.y, a.z, a.w, b.x, b.y, b.z, b.w};
  float sum = 0.f, sq = 0.f;
#pragma unroll
  for (int j = 0; j < 8; j++) { sum += xv[j]; sq += xv[j] * xv[j]; }
#pragma unroll
  for (int m = 32; m; m >>= 1) { sum += __shfl_xor(sum, m); sq += __shfl_xor(sq, m); }
  __shared__ float red[8];
  int lane = t & 63, wid = t >> 6;
  if (!lane) { red[wid] = sum; red[wid + 4] = sq; }
  __syncthreads();
  float ts = red[0] + red[1] + red[2] + red[3];
  float tq = red[4] + red[5] + red[6] + red[7];
  float mean = ts * (1.f / HS);
  float var = tq * (1.f / HS) - mean * mean;
  float inv = rsqrtf(var + 1e-6f);
  int c0 = t * 8;
  bf16x8 ov;
#pragma unroll
  for (int j = 0; j < 8; j++) {
    int c = c0 + j;
    float v = ((xv[j] - mean) * inv * ls[c] + lb[c]) * (1.f + sc[c]) + sh[c];
    ov[j] = (bf16)v;
  }
  *(bf16x8*)(out + (size_t)r * HS + c0) = ov;
}

// ---------------- GEMM: A[2560][K] bf16 @ BT[N][K] bf16, dual-stream weights ----------------
// MODE 0: out bf16 = acc+bias ; 1: f32 res+gate*(acc+bias) ; 2: bf16 gelu ; 3: f32 res+gate*(..)
template <int MODE>
__global__ __launch_bounds__(256) void k_gemm(
    const bf16* __restrict__ A, int K, int N,
    const bf16* __restrict__ BT0, const bf16* __restrict__ BT1,
    const float* __restrict__ bias0, const float* __restrict__ bias1,
    const float* __restrict__ gate0, const float* __restrict__ gate1,
    const float* __restrict__ res0, const float* __restrict__ res1,
    void* __restrict__ out0, void* __restrict__ out1) {
  __shared__ bf16 As[128 * 32];
  __shared__ bf16 Bs[128 * 32];
  int tid = threadIdx.x;
  int bn = blockIdx.x, bm = blockIdx.y;
  int strm = (bm * 128) >= LT;
  int lm = bm * 128 - strm * LT;
  const bf16* BT = strm ? BT1 : BT0;
  const float* bias = strm ? bias1 : bias0;
  int lane = tid & 63, wid = tid >> 6;
  int wr = wid >> 1, wc = wid & 1;
  int sr = tid >> 2, sc8 = (tid & 3) * 8;
  const bf16* Ag = A + (size_t)(bm * 128 + sr) * K + sc8;
  const bf16* Bg = BT + (size_t)(bn * 128 + sr) * K + sc8;
  bf16* As_dst = As + wid * 512;  // wave-uniform; HW adds lane*16B
  bf16* Bs_dst = Bs + wid * 512;
  f32x4 acc[4][4] = {};
  for (int k0 = 0; k0 < K; k0 += 32) {
    __syncthreads();
    gl_lds16(Ag + k0, As_dst);
    gl_lds16(Ag + (size_t)64 * K + k0, As_dst + 2048);
    gl_lds16(Bg + k0, Bs_dst);
    gl_lds16(Bg + (size_t)64 * K + k0, Bs_dst + 2048);
    __syncthreads();
    bf16x8 af[4], bfr[4];
    int r16 = lane & 15, kc8 = (lane >> 4) * 8;
#pragma unroll
    for (int m = 0; m < 4; m++) af[m] = *(const bf16x8*)&As[(wr * 64 + m * 16 + r16) * 32 + kc8];
#pragma unroll
    for (int n = 0; n < 4; n++) bfr[n] = *(const bf16x8*)&Bs[(wc * 64 + n * 16 + r16) * 32 + kc8];
#pragma unroll
    for (int m = 0; m < 4; m++)
#pragma unroll
      for (int n = 0; n < 4; n++)
        acc[m][n] = mfma16(af[m], bfr[n], acc[m][n]);
  }
  int col = lane & 15, rb = (lane >> 4) * 4;
#pragma unroll
  for (int m = 0; m < 4; m++) {
#pragma unroll
    for (int n = 0; n < 4; n++) {
      int gn = bn * 128 + wc * 64 + n * 16 + col;
      float bv = bias[gn];
#pragma unroll
      for (int r = 0; r < 4; r++) {
        int gr = lm + wr * 64 + m * 16 + rb + r;
        size_t oi = (size_t)gr * N + gn;
        float v = acc[m][n][r] + bv;
        if (MODE == 0) {
          ((bf16*)(strm ? out1 : out0))[oi] = (bf16)v;
        } else if (MODE == 2) {
          float g = 0.5f * v * (1.f + tanhf(0.7978845608028654f * (v + 0.044715f * v * v * v)));
          ((bf16*)(strm ? out1 : out0))[oi] = (bf16)g;
        } else {
          const float* gate = strm ? gate1 : gate0;
          const float* res = strm ? res1 : res0;
          float o = res[oi] + gate[gn] * v;
          ((float*)(strm ? out1 : out0))[oi] = o;
        }
      }
    }
  }
}

// ---------------- qkv post: RMS norm (q,k) + RoPE + scale ----------------
__global__ __launch_bounds__(256) void k_qkv_post(
    const bf16* __restrict__ y, const float* __restrict__ pe,
    const float* __restrict__ qn0, const float* __restrict__ kn0,
    const float* __restrict__ qn1, const float* __restrict__ kn1,
    bf16* __restrict__ qh, bf16* __restrict__ kh) {
  int wv = (int)((blockIdx.x * 256 + threadIdx.x) >> 6);
  int lane = threadIdx.x & 63;
  int head = wv / LQ, l = wv - head * LQ;
  const bf16* yr = y + (size_t)l * (3 * HS) + head * HD;
  float q0 = (float)yr[2 * lane], q1 = (float)yr[2 * lane + 1];
  float k0 = (float)yr[HS + 2 * lane], k1 = (float)yr[HS + 2 * lane + 1];
  float sqs = q0 * q0 + q1 * q1, sks = k0 * k0 + k1 * k1;
#pragma unroll
  for (int m = 1; m < 64; m <<= 1) { sqs += __shfl_xor(sqs, m); sks += __shfl_xor(sks, m); }
  float rq = rsqrtf(sqs * (1.f / HD) + 1e-6f);
  float rk = rsqrtf(sks * (1.f / HD) + 1e-6f);
  int strm = l >= LT;
  const float* qn = strm ? qn1 : qn0;
  const float* kn = strm ? kn1 : kn0;
  float e0 = q0 * rq * qn[2 * lane], e1 = q1 * rq * qn[2 * lane + 1];
  float f0 = k0 * rk * kn[2 * lane], f1 = k1 * rk * kn[2 * lane + 1];
  float4 p = *(const float4*)(pe + ((size_t)l * 64 + lane) * 4);
  const float scl = 0.08838834764831845f;  // 128^-0.5 folded into q
  size_t qi = ((size_t)head * LQ + l) * HD + 2 * lane;
  bf16x2 qv = {(bf16)((p.x * e0 + p.y * e1) * scl), (bf16)((p.z * e0 + p.w * e1) * scl)};
  bf16x2 kv = {(bf16)(p.x * f0 + p.y * f1), (bf16)(p.z * f0 + p.w * f1)};
  *(bf16x2*)(qh + qi) = qv;
  *(bf16x2*)(kh + qi) = kv;
}

// ---------------- V transpose: y v-part [l][head*HD+d] -> vT [head][d][l] ----------------
__global__ __launch_bounds__(256) void k_vtrans(const bf16* __restrict__ y,
                                                bf16* __restrict__ vT) {
  __shared__ bf16 t[32][34];
  int head = blockIdx.y >> 2, dt = blockIdx.y & 3;
  int tx = threadIdx.x & 31, ty = threadIdx.x >> 5;
  int l0 = blockIdx.x * 32, d0 = dt * 32;
  for (int i = 0; i < 32; i += 8)
    t[ty + i][tx] = y[(size_t)(l0 + ty + i) * (3 * HS) + 2 * HS + head * HD + d0 + tx];
  __syncthreads();
  for (int i = 0; i < 32; i += 8)
    vT[(size_t)(head * HD + d0 + ty + i) * LQ + l0 + tx] = t[tx][ty + i];
}

// ---------------- flash attention, KV-split x2, no block barriers ----------------
// grid 1280: head = b/80, half = (b%80)/40, qb = b%40. 4 waves x 16 q-rows.
__global__ __launch_bounds__(256, 4) void k_attn(
    const bf16* __restrict__ Q, const bf16* __restrict__ Kh,
    const bf16* __restrict__ VT, bf16* __restrict__ Op0, bf16* __restrict__ Op1,
    float* __restrict__ ml) {
  __shared__ bf16 P[4][16 * 40];
  int tid = threadIdx.x, lane = tid & 63, w = tid >> 6;
  int b = blockIdx.x;
  int head = b / 80, rem = b % 80;
  int half = rem / 40, qb = rem % 40;
  int qr = qb * 64 + w * 16;
  int r16 = lane & 15, kc = lane >> 4;
  const bf16* qp = Q + ((size_t)head * LQ + qr + r16) * HD + kc * 8;
  bf16x8 qf[4];
#pragma unroll
  for (int c = 0; c < 4; c++) qf[c] = *(const bf16x8*)(qp + c * 32);
  f32x4 O[8] = {};
  float mr[4], lr[4];
#pragma unroll
  for (int i = 0; i < 4; i++) { mr[i] = -1e30f; lr[i] = 0.f; }
  bf16* pl = &P[w][0];
  const bf16* kbase = Kh + ((size_t)head * LQ + half * 1280) * HD;
  const bf16* vbase = VT + (size_t)head * HD * LQ + half * 1280;
  for (int t = 0; t < 40; t++) {
    const bf16* kp = kbase + (size_t)(t * 32 + r16) * HD + kc * 8;
    f32x4 S0 = {}, S1 = {};
#pragma unroll
    for (int c = 0; c < 4; c++) {
      bf16x8 ka = *(const bf16x8*)(kp + c * 32);
      bf16x8 kb = *(const bf16x8*)(kp + 16 * HD + c * 32);
      S0 = mfma16(qf[c], ka, S0);
      S1 = mfma16(qf[c], kb, S1);
    }
    // issue V loads (first group) before softmax so VALU hides their latency
    const bf16* vp = vbase + (size_t)r16 * LQ + t * 32 + kc * 8;
    bf16x8 vf0[4];
#pragma unroll
    for (int n = 0; n < 4; n++) vf0[n] = *(const bf16x8*)(vp + (size_t)n * 16 * LQ);
    float alpha[4];
#pragma unroll
    for (int i = 0; i < 4; i++) {
      float mx = fmaxf(S0[i], S1[i]);
#pragma unroll
      for (int m = 8; m; m >>= 1) mx = fmaxf(mx, __shfl_xor(mx, m));
      float mn = fmaxf(mr[i], mx);
      float p0 = __expf(S0[i] - mn), p1 = __expf(S1[i] - mn);
      float rs = p0 + p1;
#pragma unroll
      for (int m = 8; m; m >>= 1) rs += __shfl_xor(rs, m);
      alpha[i] = __expf(mr[i] - mn);
      lr[i] = lr[i] * alpha[i] + rs;
      mr[i] = mn;
      pl[(4 * kc + i) * 40 + r16] = (bf16)p0;
      pl[(4 * kc + i) * 40 + 16 + r16] = (bf16)p1;
    }
    // per-wave LDS write->read: in-order DS ops + compiler lgkmcnt, no barrier needed
    bf16x8 pf = *(const bf16x8*)&pl[r16 * 40 + kc * 8];
#pragma unroll
    for (int n = 0; n < 4; n++) {
      f32x4 o = O[n];
#pragma unroll
      for (int i = 0; i < 4; i++) o[i] *= alpha[i];
      O[n] = mfma16(pf, vf0[n], o);
    }
    bf16x8 vf1[4];
#pragma unroll
    for (int n = 0; n < 4; n++) vf1[n] = *(const bf16x8*)(vp + (size_t)(4 + n) * 16 * LQ);
#pragma unroll
    for (int n = 0; n < 4; n++) {
      f32x4 o = O[4 + n];
#pragma unroll
      for (int i = 0; i < 4; i++) o[i] *= alpha[i];
      O[4 + n] = mfma16(pf, vf1[n], o);
    }
  }
  bf16* Op = half ? Op1 : Op0;
  const int NL = NH * LQ;
#pragma unroll
  for (int n = 0; n < 8; n++)
#pragma unroll
    for (int i = 0; i < 4; i++)
      Op[((size_t)head * LQ + qr + 4 * kc + i) * HD + n * 16 + r16] = (bf16)O[n][i];
  if (r16 == 0) {
#pragma unroll
    for (int i = 0; i < 4; i++) {
      int idx = head * LQ + qr + 4 * kc + i;
      ml[(size_t)(half * 2 + 0) * NL + idx] = mr[i];
      ml[(size_t)(half * 2 + 1) * NL + idx] = lr[i];
    }
  }
}

// ---------------- combine 2 KV-halves -> attnb [l][head*HD+d] bf16 ----------------
__global__ __launch_bounds__(256) void k_attn_combine(
    const bf16* __restrict__ Op0, const bf16* __restrict__ Op1,
    const float* __restrict__ ml, bf16* __restrict__ out) {
  int lane = threadIdx.x & 63, w = threadIdx.x >> 6;
  int row = blockIdx.x * 4 + w;  // head*LQ + l
  int head = row / LQ, l = row - head * LQ;
  const int NL = NH * LQ;
  float m0 = ml[row], l0 = ml[NL + row];
  float m1 = ml[2 * NL + row], l1 = ml[3 * NL + row];
  float m = fmaxf(m0, m1);
  float w0 = __expf(m0 - m), w1 = __expf(m1 - m);
  float inv = 1.f / (w0 * l0 + w1 * l1);
  size_t oi = (size_t)row * HD + 2 * lane;
  bf16x2 a = *(const bf16x2*)(Op0 + oi);
  bf16x2 c = *(const bf16x2*)(Op1 + oi);
  bf16x2 ov = {(bf16)((w0 * (float)a[0] + w1 * (float)c[0]) * inv),
               (bf16)((w0 * (float)a[1] + w1 * (float)c[1]) * inv)};
  *(bf16x2*)(out + (size_t)l * HS + head * HD + 2 * lane) = ov;
}

// ---------------- launch ----------------
extern "C" void kernel_launch(void* const* d_in, const int* in_sizes, int n_in,
                              void* d_out, int out_size, void* d_ws, size_t ws_size,
                              hipStream_t stream) {
  const float* img = (const float*)d_in[0];
  const float* txt = (const float*)d_in[1];
  const float* vec = (const float*)d_in[2];
  const float* pe = (const float*)d_in[3];
#define PARAM(i) ((const float*)d_in[i])

  char* ws = (char*)d_ws;
  size_t off = 0;
  auto alloc = [&](size_t b) { void* p = ws + off; off += (b + 255) & ~(size_t)255; return p; };
  float* silu_s = (float*)alloc((size_t)HS * 4);
  float* mpart = (float*)alloc((size_t)8 * 2 * 12288 * 4);
  float* mod = (float*)alloc((size_t)2 * 6 * HS * 4);
  bf16* qkvT0 = (bf16*)alloc((size_t)3 * HS * HS * 2);
  bf16* qkvT1 = (bf16*)alloc((size_t)3 * HS * HS * 2);
  bf16* projT0 = (bf16*)alloc((size_t)HS * HS * 2);
  bf16* projT1 = (bf16*)alloc((size_t)HS * HS * 2);
  bf16* mlp1T0 = (bf16*)alloc((size_t)MLP_D * HS * 2);
  bf16* mlp1T1 = (bf16*)alloc((size_t)MLP_D * HS * 2);
  bf16* mlp2T0 = (bf16*)alloc((size_t)HS * MLP_D * 2);
  bf16* mlp2T1 = (bf16*)alloc((size_t)HS * MLP_D * 2);
  bf16* xm = (bf16*)alloc((size_t)LQ * HS * 2);
  bf16* y = (bf16*)alloc((size_t)LQ * 3 * HS * 2);
  bf16* qh = (bf16*)alloc((size_t)NH * LQ * HD * 2);
  bf16* kh = (bf16*)alloc((size_t)NH * LQ * HD * 2);
  bf16* vT = (bf16*)alloc((size_t)NH * HD * LQ * 2);
  bf16* attnb = (bf16*)alloc((size_t)LQ * HS * 2);
  float* x2 = (float*)alloc((size_t)LQ * HS * 4);
  bf16* xm2 = (bf16*)alloc((size_t)LQ * HS * 2);
  bf16* h = (bf16*)alloc((size_t)LQ * MLP_D * 2);
  float* ml = (float*)alloc((size_t)4 * NH * LQ * 4);
  // aliases: y (31.4MB) dead after k_vtrans; h (42MB) first written at step 9.
  bf16* Op0 = y;   // 10.5MB partial, half 0
  bf16* Op1 = h;   // 10.5MB partial, half 1
  (void)ws_size; (void)in_sizes; (void)n_in; (void)out_size;

  const float* t_mod = mod;
  const float* i_mod = mod + 6 * HS;

  // 1) modulation vectors
  k_silu<<<HS / 256, 256, 0, stream>>>(vec, silu_s);
  k_mod_partial<<<dim3(96, 8), 256, 0, stream>>>(silu_s, PARAM(20), PARAM(4), mpart);
  k_mod_reduce<<<96, 256, 0, stream>>>(mpart, PARAM(21), PARAM(5), mod);

  // 2) weight transpose+cvt
  k_transpose_cvt<<<dim3(3 * HS / 32, HS / 32), 256, 0, stream>>>(PARAM(24), qkvT0, HS, 3 * HS);
  k_transpose_cvt<<<dim3(3 * HS / 32, HS / 32), 256, 0, stream>>>(PARAM(8), qkvT1, HS, 3 * HS);
  k_transpose_cvt<<<dim3(HS / 32, HS / 32), 256, 0, stream>>>(PARAM(28), projT0, HS, HS);
  k_transpose_cvt<<<dim3(HS / 32, HS / 32), 256, 0, stream>>>(PARAM(12), projT1, HS, HS);
  k_transpose_cvt<<<dim3(MLP_D / 32, HS / 32), 256, 0, stream>>>(PARAM(32), mlp1T0, HS, MLP_D);
  k_transpose_cvt<<<dim3(MLP_D / 32, HS / 32), 256, 0, stream>>>(PARAM(16), mlp1T1, HS, MLP_D);
  k_transpose_cvt<<<dim3(HS / 32, MLP_D / 32), 256, 0, stream>>>(PARAM(34), mlp2T0, MLP_D, HS);
  k_transpose_cvt<<<dim3(HS / 32, MLP_D / 32), 256, 0, stream>>>(PARAM(18), mlp2T1, MLP_D, HS);

  // 3) LN1 + modulate
  k_ln_mod<<<LQ, 256, 0, stream>>>(txt, img, PARAM(22), PARAM(23), PARAM(6), PARAM(7),
                                   t_mod, i_mod, 0, 1, xm);

  // 4) qkv GEMM
  k_gemm<0><<<dim3(3 * HS / 128, LQ / 128), 256, 0, stream>>>(
      xm, HS, 3 * HS, qkvT0, qkvT1, PARAM(25), PARAM(9),
      nullptr, nullptr, nullptr, nullptr, y, y + (size_t)LT * 3 * HS);

  // 5) RMS + RoPE ; V transpose
  k_qkv_post<<<NH * LQ / 4, 256, 0, stream>>>(y, pe, PARAM(26), PARAM(27), PARAM(10), PARAM(11),
                                              qh, kh);
  k_vtrans<<<dim3(LQ / 32, NH * 4), 256, 0, stream>>>(y, vT);

  // 6) attention (KV-split x2) + combine
  k_attn<<<NH * 80, 256, 0, stream>>>(qh, kh, vT, Op0, Op1, ml);
  k_attn_combine<<<NH * LQ / 4, 256, 0, stream>>>(Op0, Op1, ml, attnb);

  // 7) proj GEMM + gated residual
  k_gemm<1><<<dim3(HS / 128, LQ / 128), 256, 0, stream>>>(
      attnb, HS, HS, projT0, projT1, PARAM(29), PARAM(13),
      t_mod + 2 * HS, i_mod + 2 * HS, txt, img, x2, x2 + (size_t)LT * HS);

  // 8) LN2 + modulate
  k_ln_mod<<<LQ, 256, 0, stream>>>(x2, x2 + (size_t)LT * HS, PARAM(30), PARAM(31), PARAM(14),
                                   PARAM(15), t_mod, i_mod, 3, 4, xm2);

  // 9) MLP1 + gelu
  k_gemm<2><<<dim3(MLP_D / 128, LQ / 128), 256, 0, stream>>>(
      xm2, HS, MLP_D, mlp1T0, mlp1T1, PARAM(33), PARAM(17),
      nullptr, nullptr, nullptr, nullptr, h, h + (size_t)LT * MLP_D);

  // 10) MLP2 + gated residual -> d_out (img first)
  float* out_img = (float*)d_out;
  float* out_txt = (float*)d_out + (size_t)LI * HS;
  k_gemm<3><<<dim3(HS / 128, LQ / 128), 256, 0, stream>>>(
      h, MLP_D, HS, mlp2T0, mlp2T1, PARAM(35), PARAM(19),
      t_mod + 5 * HS, i_mod + 5 * HS, x2, x2 + (size_t)LT * HS, out_txt, out_img);
}

// Round 3
// 932.937 us; speedup vs baseline: 1.2663x; 1.2284x over previous
//
#include <hip/hip_runtime.h>
#include <hip/hip_bf16.h>
#include <math.h>

typedef __bf16 bf16;
typedef __bf16 bf16x2 __attribute__((ext_vector_type(2)));
typedef __bf16 bf16x8 __attribute__((ext_vector_type(8)));
typedef float f32x4 __attribute__((ext_vector_type(4)));

#define HS 2048
#define NH 16
#define HD 128
#define LT 512
#define LI 2048
#define LQ 2560
#define MLP_D 8192
#define SPLIT 4
#define KVS (LQ / SPLIT)  // 640 kv per split
#define KVBLK 32
#define NTILES (KVS / KVBLK)  // 20

__device__ __forceinline__ f32x4 mfma16(bf16x8 a, bf16x8 b, f32x4 c) {
  return __builtin_amdgcn_mfma_f32_16x16x32_bf16(a, b, c, 0, 0, 0);
}

// async global->LDS, 16B per lane; lds dest must be wave-uniform base (+lane*16 by HW)
__device__ __forceinline__ void gl_lds16(const bf16* g, bf16* l) {
  __builtin_amdgcn_global_load_lds((const __attribute__((address_space(1))) void*)g,
                                   (__attribute__((address_space(3))) void*)l, 16, 0, 0);
}

// ---------------- silu(vec) ----------------
__global__ void k_silu(const float* __restrict__ v, float* __restrict__ s) {
  int i = blockIdx.x * 256 + threadIdx.x;
  float x = v[i];
  s[i] = x / (1.f + expf(-x));
}

// ---------------- mod GEMV: silu(vec) @ mod_w, 2-pass (deterministic) ----------------
__global__ __launch_bounds__(256) void k_mod_partial(
    const float* __restrict__ s, const float* __restrict__ w_txt,
    const float* __restrict__ w_img, float* __restrict__ part) {
  int strm = blockIdx.x / 48;
  int n = (blockIdx.x % 48) * 256 + threadIdx.x;
  const float* w = strm ? w_img : w_txt;
  int k0 = blockIdx.y * 256;
  __shared__ float sl[256];
  sl[threadIdx.x] = s[k0 + threadIdx.x];
  __syncthreads();
  float acc = 0.f;
  for (int k = 0; k < 256; k++)
    acc += sl[k] * w[(size_t)(k0 + k) * 12288 + n];
  part[((size_t)blockIdx.y * 2 + strm) * 12288 + n] = acc;
}

__global__ __launch_bounds__(256) void k_mod_reduce(
    const float* __restrict__ part, const float* __restrict__ b_txt,
    const float* __restrict__ b_img, float* __restrict__ mod) {
  int strm = blockIdx.x / 48;
  int n = (blockIdx.x % 48) * 256 + threadIdx.x;
  float acc = strm ? b_img[n] : b_txt[n];
  for (int kc = 0; kc < 8; kc++)
    acc += part[((size_t)kc * 2 + strm) * 12288 + n];
  mod[(size_t)strm * 12288 + n] = acc;
}

// ---------------- weight transpose + fp32->bf16 : src[R][C] -> dst[C][R] ----------------
__global__ __launch_bounds__(256) void k_transpose_cvt(
    const float* __restrict__ src, bf16* __restrict__ dst, int R, int C) {
  __shared__ float t[32][33];
  int tx = threadIdx.x & 31, ty = threadIdx.x >> 5;
  int c0 = blockIdx.x * 32, r0 = blockIdx.y * 32;
  for (int i = 0; i < 32; i += 8)
    t[ty + i][tx] = src[(size_t)(r0 + ty + i) * C + c0 + tx];
  __syncthreads();
  for (int i = 0; i < 32; i += 8)
    dst[(size_t)(c0 + ty + i) * R + r0 + tx] = (bf16)t[tx][ty + i];
}

// ---------------- LayerNorm + modulate -> bf16 ----------------
__global__ __launch_bounds__(256) void k_ln_mod(
    const float* __restrict__ x0, const float* __restrict__ x1,
    const float* __restrict__ ls0, const float* __restrict__ lb0,
    const float* __restrict__ ls1, const float* __restrict__ lb1,
    const float* __restrict__ mod0, const float* __restrict__ mod1,
    int shidx, int scidx, bf16* __restrict__ out) {
  int r = blockIdx.x;
  int strm = r >= LT;
  const float* x = strm ? (x1 + (size_t)(r - LT) * HS) : (x0 + (size_t)r * HS);
  const float* ls = strm ? ls1 : ls0;
  const float* lb = strm ? lb1 : lb0;
  const float* md = strm ? mod1 : mod0;
  const float* sh = md + (size_t)shidx * HS;
  const float* sc = md + (size_t)scidx * HS;
  int t = threadIdx.x;
  float4 a = ((const float4*)x)[t * 2];
  float4 b = ((const float4*)x)[t * 2 + 1];
  float xv[8] = {a.x, a.y, a.z, a.w, b.x, b.y, b.z, b.w};
  float sum = 0.f, sq = 0.f;
#pragma unroll
  for (int j = 0; j < 8; j++) { sum += xv[j]; sq += xv[j] * xv[j]; }
#pragma unroll
  for (int m = 32; m; m >>= 1) { sum += __shfl_xor(sum, m); sq += __shfl_xor(sq, m); }
  __shared__ float red[8];
  int lane = t & 63, wid = t >> 6;
  if (!lane) { red[wid] = sum; red[wid + 4] = sq; }
  __syncthreads();
  float ts = red[0] + red[1] + red[2] + red[3];
  float tq = red[4] + red[5] + red[6] + red[7];
  float mean = ts * (1.f / HS);
  float var = tq * (1.f / HS) - mean * mean;
  float inv = rsqrtf(var + 1e-6f);
  int c0 = t * 8;
  bf16x8 ov;
#pragma unroll
  for (int j = 0; j < 8; j++) {
    int c = c0 + j;
    float v = ((xv[j] - mean) * inv * ls[c] + lb[c]) * (1.f + sc[c]) + sh[c];
    ov[j] = (bf16)v;
  }
  *(bf16x8*)(out + (size_t)r * HS + c0) = ov;
}

// ---------------- GEMM: A[2560][K] bf16 @ BT[N][K] bf16, dual-stream weights ----------------
template <int MODE>
__global__ __launch_bounds__(256) void k_gemm(
    const bf16* __restrict__ A, int K, int N,
    const bf16* __restrict__ BT0, const bf16* __restrict__ BT1,
    const float* __restrict__ bias0, const float* __restrict__ bias1,
    const float* __restrict__ gate0, const float* __restrict__ gate1,
    const float* __restrict__ res0, const float* __restrict__ res1,
    void* __restrict__ out0, void* __restrict__ out1) {
  __shared__ bf16 As[128 * 32];
  __shared__ bf16 Bs[128 * 32];
  int tid = threadIdx.x;
  int bn = blockIdx.x, bm = blockIdx.y;
  int strm = (bm * 128) >= LT;
  int lm = bm * 128 - strm * LT;
  const bf16* BT = strm ? BT1 : BT0;
  const float* bias = strm ? bias1 : bias0;
  int lane = tid & 63, wid = tid >> 6;
  int wr = wid >> 1, wc = wid & 1;
  int sr = tid >> 2, sc8 = (tid & 3) * 8;
  const bf16* Ag = A + (size_t)(bm * 128 + sr) * K + sc8;
  const bf16* Bg = BT + (size_t)(bn * 128 + sr) * K + sc8;
  bf16* As_dst = As + wid * 512;
  bf16* Bs_dst = Bs + wid * 512;
  f32x4 acc[4][4] = {};
  for (int k0 = 0; k0 < K; k0 += 32) {
    __syncthreads();
    gl_lds16(Ag + k0, As_dst);
    gl_lds16(Ag + (size_t)64 * K + k0, As_dst + 2048);
    gl_lds16(Bg + k0, Bs_dst);
    gl_lds16(Bg + (size_t)64 * K + k0, Bs_dst + 2048);
    __syncthreads();
    bf16x8 af[4], bfr[4];
    int r16 = lane & 15, kc8 = (lane >> 4) * 8;
#pragma unroll
    for (int m = 0; m < 4; m++) af[m] = *(const bf16x8*)&As[(wr * 64 + m * 16 + r16) * 32 + kc8];
#pragma unroll
    for (int n = 0; n < 4; n++) bfr[n] = *(const bf16x8*)&Bs[(wc * 64 + n * 16 + r16) * 32 + kc8];
#pragma unroll
    for (int m = 0; m < 4; m++)
#pragma unroll
      for (int n = 0; n < 4; n++)
        acc[m][n] = mfma16(af[m], bfr[n], acc[m][n]);
  }
  int col = lane & 15, rb = (lane >> 4) * 4;
#pragma unroll
  for (int m = 0; m < 4; m++) {
#pragma unroll
    for (int n = 0; n < 4; n++) {
      int gn = bn * 128 + wc * 64 + n * 16 + col;
      float bv = bias[gn];
#pragma unroll
      for (int r = 0; r < 4; r++) {
        int gr = lm + wr * 64 + m * 16 + rb + r;
        size_t oi = (size_t)gr * N + gn;
        float v = acc[m][n][r] + bv;
        if (MODE == 0) {
          ((bf16*)(strm ? out1 : out0))[oi] = (bf16)v;
        } else if (MODE == 2) {
          float g = 0.5f * v * (1.f + tanhf(0.7978845608028654f * (v + 0.044715f * v * v * v)));
          ((bf16*)(strm ? out1 : out0))[oi] = (bf16)g;
        } else {
          const float* gate = strm ? gate1 : gate0;
          const float* res = strm ? res1 : res0;
          float o = res[oi] + gate[gn] * v;
          ((float*)(strm ? out1 : out0))[oi] = o;
        }
      }
    }
  }
}

// ---------------- qkv post: RMS norm (q,k) + RoPE + scale ----------------
__global__ __launch_bounds__(256) void k_qkv_post(
    const bf16* __restrict__ y, const float* __restrict__ pe,
    const float* __restrict__ qn0, const float* __restrict__ kn0,
    const float* __restrict__ qn1, const float* __restrict__ kn1,
    bf16* __restrict__ qh, bf16* __restrict__ kh) {
  int wv = (int)((blockIdx.x * 256 + threadIdx.x) >> 6);
  int lane = threadIdx.x & 63;
  int head = wv / LQ, l = wv - head * LQ;
  const bf16* yr = y + (size_t)l * (3 * HS) + head * HD;
  float q0 = (float)yr[2 * lane], q1 = (float)yr[2 * lane + 1];
  float k0 = (float)yr[HS + 2 * lane], k1 = (float)yr[HS + 2 * lane + 1];
  float sqs = q0 * q0 + q1 * q1, sks = k0 * k0 + k1 * k1;
#pragma unroll
  for (int m = 1; m < 64; m <<= 1) { sqs += __shfl_xor(sqs, m); sks += __shfl_xor(sks, m); }
  float rq = rsqrtf(sqs * (1.f / HD) + 1e-6f);
  float rk = rsqrtf(sks * (1.f / HD) + 1e-6f);
  int strm = l >= LT;
  const float* qn = strm ? qn1 : qn0;
  const float* kn = strm ? kn1 : kn0;
  float e0 = q0 * rq * qn[2 * lane], e1 = q1 * rq * qn[2 * lane + 1];
  float f0 = k0 * rk * kn[2 * lane], f1 = k1 * rk * kn[2 * lane + 1];
  float4 p = *(const float4*)(pe + ((size_t)l * 64 + lane) * 4);
  const float scl = 0.08838834764831845f;  // 128^-0.5 folded into q
  size_t qi = ((size_t)head * LQ + l) * HD + 2 * lane;
  bf16x2 qv = {(bf16)((p.x * e0 + p.y * e1) * scl), (bf16)((p.z * e0 + p.w * e1) * scl)};
  bf16x2 kv = {(bf16)(p.x * f0 + p.y * f1), (bf16)(p.z * f0 + p.w * f1)};
  *(bf16x2*)(qh + qi) = qv;
  *(bf16x2*)(kh + qi) = kv;
}

// ---------------- V transpose: y v-part [l][head*HD+d] -> vT [head][d][l] ----------------
__global__ __launch_bounds__(256) void k_vtrans(const bf16* __restrict__ y,
                                                bf16* __restrict__ vT) {
  __shared__ bf16 t[32][34];
  int head = blockIdx.y >> 2, dt = blockIdx.y & 3;
  int tx = threadIdx.x & 31, ty = threadIdx.x >> 5;
  int l0 = blockIdx.x * 32, d0 = dt * 32;
  for (int i = 0; i < 32; i += 8)
    t[ty + i][tx] = y[(size_t)(l0 + ty + i) * (3 * HS) + 2 * HS + head * HD + d0 + tx];
  __syncthreads();
  for (int i = 0; i < 32; i += 8)
    vT[(size_t)(head * HD + d0 + ty + i) * LQ + l0 + tx] = t[tx][ty + i];
}

// ---------------- flash attention: KV-split x4, K/V staged in LDS (shared by 4 waves) --------
// grid = NH*SPLIT*40, ordered qb-fastest so consecutive blocks share K/V tiles in L2.
// K LDS is XOR-swizzled (slot^(row&7), 16B slots) via pre-swizzled global_load_lds source.
__global__ __launch_bounds__(256, 5) void k_attn(
    const bf16* __restrict__ Q, const bf16* __restrict__ Kh,
    const bf16* __restrict__ VT, bf16* __restrict__ Op, float* __restrict__ ml) {
  __shared__ bf16 Ks[KVBLK * 128];   // [kv][hd], 256B rows, content swizzled
  __shared__ bf16 Vs[128 * KVBLK];   // V^T [d][kv], 64B rows, linear
  __shared__ bf16 P[4][16 * 34];     // per-wave [16 q][32 kv pad 34]
  int tid = threadIdx.x, lane = tid & 63, w = tid >> 6;
  int b = blockIdx.x;
  int qb = b % 40;
  int split = (b / 40) % SPLIT;
  int head = b / (40 * SPLIT);
  int qr = qb * 64 + w * 16;
  int r16 = lane & 15, g = lane >> 4;
  const bf16* qp = Q + ((size_t)head * LQ + qr + r16) * HD + g * 8;
  bf16x8 qf[4];
#pragma unroll
  for (int c = 0; c < 4; c++) qf[c] = *(const bf16x8*)(qp + c * 32);
  f32x4 O[8] = {};
  float mr[4], lr[4];
#pragma unroll
  for (int i = 0; i < 4; i++) { mr[i] = -1e30f; lr[i] = 0.f; }
  bf16* pl = &P[w][0];
  const bf16* kbase = Kh + ((size_t)head * LQ + split * KVS) * HD;
  const bf16* vbase = VT + (size_t)head * HD * LQ + split * KVS;
  // per-lane staging offsets
  int krow0 = w * 8 + (lane >> 4);          // + i*4
  int kslot = lane & 15;
  int vrow0 = w * 32 + (lane >> 2);         // + i*16
  int vcol = (lane & 3) * 8;
  for (int t = 0; t < NTILES; t++) {
    int kv0 = t * KVBLK;
#pragma unroll
    for (int i = 0; i < 2; i++) {
      int krow = krow0 + i * 4;
      gl_lds16(kbase + (size_t)(kv0 + krow) * HD + ((kslot ^ (krow & 7)) << 3),
               Ks + (w * 8 + i * 4) * 128);
      int vrow = vrow0 + i * 16;
      gl_lds16(vbase + (size_t)vrow * LQ + kv0 + vcol,
               Vs + (w * 32 + i * 16) * KVBLK);
    }
    __syncthreads();
    // S = Q K^T  (rows j*16.., swizzled slot)
    f32x4 S0 = {}, S1 = {};
    int sw = (r16 & 7);
#pragma unroll
    for (int c = 0; c < 4; c++) {
      int slot = ((4 * c + g) ^ sw) << 3;
      bf16x8 ka = *(const bf16x8*)&Ks[r16 * 128 + slot];
      bf16x8 kb = *(const bf16x8*)&Ks[(16 + r16) * 128 + slot];
      S0 = mfma16(qf[c], ka, S0);
      S1 = mfma16(qf[c], kb, S1);
    }
    float alpha[4];
#pragma unroll
    for (int i = 0; i < 4; i++) {
      float mx = fmaxf(S0[i], S1[i]);
#pragma unroll
      for (int m = 8; m; m >>= 1) mx = fmaxf(mx, __shfl_xor(mx, m));
      float mn = fmaxf(mr[i], mx);
      float p0 = __expf(S0[i] - mn), p1 = __expf(S1[i] - mn);
      float rs = p0 + p1;
#pragma unroll
      for (int m = 8; m; m >>= 1) rs += __shfl_xor(rs, m);
      alpha[i] = __expf(mr[i] - mn);
      lr[i] = lr[i] * alpha[i] + rs;
      mr[i] = mn;
      pl[(4 * g + i) * 34 + r16] = (bf16)p0;
      pl[(4 * g + i) * 34 + 16 + r16] = (bf16)p1;
    }
    // PV from LDS (per-wave P; in-wave DS ordering handled by compiler waits)
    bf16x8 pf = *(const bf16x8*)&pl[r16 * 34 + g * 8];
#pragma unroll
    for (int n = 0; n < 8; n++) {
      f32x4 o = O[n];
#pragma unroll
      for (int i = 0; i < 4; i++) o[i] *= alpha[i];
      bf16x8 vf = *(const bf16x8*)&Vs[(n * 16 + r16) * KVBLK + g * 8];
      O[n] = mfma16(pf, vf, o);
    }
    __syncthreads();
  }
  const int NL = NH * LQ;
  bf16* op = Op + (size_t)split * NL * HD;
#pragma unroll
  for (int n = 0; n < 8; n++)
#pragma unroll
    for (int i = 0; i < 4; i++)
      op[((size_t)head * LQ + qr + 4 * g + i) * HD + n * 16 + r16] = (bf16)O[n][i];
  if (r16 == 0) {
#pragma unroll
    for (int i = 0; i < 4; i++) {
      int idx = head * LQ + qr + 4 * g + i;
      ml[(size_t)(split * 2 + 0) * NL + idx] = mr[i];
      ml[(size_t)(split * 2 + 1) * NL + idx] = lr[i];
    }
  }
}

// ---------------- combine SPLIT KV-parts -> attnb [l][head*HD+d] bf16 ----------------
__global__ __launch_bounds__(256) void k_attn_combine(
    const bf16* __restrict__ Op, const float* __restrict__ ml, bf16* __restrict__ out) {
  int lane = threadIdx.x & 63, w = threadIdx.x >> 6;
  int row = blockIdx.x * 4 + w;  // head*LQ + l
  int head = row / LQ, l = row - head * LQ;
  const int NL = NH * LQ;
  float ms[SPLIT], ls[SPLIT], m = -1e30f;
#pragma unroll
  for (int s = 0; s < SPLIT; s++) {
    ms[s] = ml[(size_t)(s * 2) * NL + row];
    ls[s] = ml[(size_t)(s * 2 + 1) * NL + row];
    m = fmaxf(m, ms[s]);
  }
  float wsum = 0.f, wgt[SPLIT];
#pragma unroll
  for (int s = 0; s < SPLIT; s++) { wgt[s] = __expf(ms[s] - m); wsum += wgt[s] * ls[s]; }
  float inv = 1.f / wsum;
  size_t oi = (size_t)row * HD + 2 * lane;
  float a0 = 0.f, a1 = 0.f;
#pragma unroll
  for (int s = 0; s < SPLIT; s++) {
    bf16x2 v = *(const bf16x2*)(Op + (size_t)s * NL * HD + oi);
    a0 += wgt[s] * (float)v[0];
    a1 += wgt[s] * (float)v[1];
  }
  bf16x2 ov = {(bf16)(a0 * inv), (bf16)(a1 * inv)};
  *(bf16x2*)(out + (size_t)l * HS + head * HD + 2 * lane) = ov;
}

// ---------------- launch ----------------
extern "C" void kernel_launch(void* const* d_in, const int* in_sizes, int n_in,
                              void* d_out, int out_size, void* d_ws, size_t ws_size,
                              hipStream_t stream) {
  const float* img = (const float*)d_in[0];
  const float* txt = (const float*)d_in[1];
  const float* vec = (const float*)d_in[2];
  const float* pe = (const float*)d_in[3];
#define PARAM(i) ((const float*)d_in[i])

  char* ws = (char*)d_ws;
  size_t off = 0;
  auto alloc = [&](size_t b) { void* p = ws + off; off += (b + 255) & ~(size_t)255; return p; };
  float* silu_s = (float*)alloc((size_t)HS * 4);
  float* mpart = (float*)alloc((size_t)8 * 2 * 12288 * 4);
  float* mod = (float*)alloc((size_t)2 * 6 * HS * 4);
  bf16* qkvT0 = (bf16*)alloc((size_t)3 * HS * HS * 2);
  bf16* qkvT1 = (bf16*)alloc((size_t)3 * HS * HS * 2);
  bf16* projT0 = (bf16*)alloc((size_t)HS * HS * 2);
  bf16* projT1 = (bf16*)alloc((size_t)HS * HS * 2);
  bf16* mlp1T0 = (bf16*)alloc((size_t)MLP_D * HS * 2);
  bf16* mlp1T1 = (bf16*)alloc((size_t)MLP_D * HS * 2);
  bf16* mlp2T0 = (bf16*)alloc((size_t)HS * MLP_D * 2);
  bf16* mlp2T1 = (bf16*)alloc((size_t)HS * MLP_D * 2);
  bf16* xm = (bf16*)alloc((size_t)LQ * HS * 2);
  bf16* y = (bf16*)alloc((size_t)LQ * 3 * HS * 2);
  bf16* qh = (bf16*)alloc((size_t)NH * LQ * HD * 2);
  bf16* kh = (bf16*)alloc((size_t)NH * LQ * HD * 2);
  bf16* vT = (bf16*)alloc((size_t)NH * HD * LQ * 2);
  bf16* attnb = (bf16*)alloc((size_t)LQ * HS * 2);
  float* x2 = (float*)alloc((size_t)LQ * HS * 4);
  bf16* xm2 = (bf16*)alloc((size_t)LQ * HS * 2);
  bf16* h = (bf16*)alloc((size_t)LQ * MLP_D * 2);
  float* ml = (float*)alloc((size_t)2 * SPLIT * NH * LQ * 4);
  // h (41.9MB) is dead until step 9 -> holds the 4 attention partials (4 x 10.5MB).
  bf16* Op = h;
  (void)ws_size; (void)in_sizes; (void)n_in; (void)out_size;

  const float* t_mod = mod;
  const float* i_mod = mod + 6 * HS;

  // 1) modulation vectors
  k_silu<<<HS / 256, 256, 0, stream>>>(vec, silu_s);
  k_mod_partial<<<dim3(96, 8), 256, 0, stream>>>(silu_s, PARAM(20), PARAM(4), mpart);
  k_mod_reduce<<<96, 256, 0, stream>>>(mpart, PARAM(21), PARAM(5), mod);

  // 2) weight transpose+cvt
  k_transpose_cvt<<<dim3(3 * HS / 32, HS / 32), 256, 0, stream>>>(PARAM(24), qkvT0, HS, 3 * HS);
  k_transpose_cvt<<<dim3(3 * HS / 32, HS / 32), 256, 0, stream>>>(PARAM(8), qkvT1, HS, 3 * HS);
  k_transpose_cvt<<<dim3(HS / 32, HS / 32), 256, 0, stream>>>(PARAM(28), projT0, HS, HS);
  k_transpose_cvt<<<dim3(HS / 32, HS / 32), 256, 0, stream>>>(PARAM(12), projT1, HS, HS);
  k_transpose_cvt<<<dim3(MLP_D / 32, HS / 32), 256, 0, stream>>>(PARAM(32), mlp1T0, HS, MLP_D);
  k_transpose_cvt<<<dim3(MLP_D / 32, HS / 32), 256, 0, stream>>>(PARAM(16), mlp1T1, HS, MLP_D);
  k_transpose_cvt<<<dim3(HS / 32, MLP_D / 32), 256, 0, stream>>>(PARAM(34), mlp2T0, MLP_D, HS);
  k_transpose_cvt<<<dim3(HS / 32, MLP_D / 32), 256, 0, stream>>>(PARAM(18), mlp2T1, MLP_D, HS);

  // 3) LN1 + modulate
  k_ln_mod<<<LQ, 256, 0, stream>>>(txt, img, PARAM(22), PARAM(23), PARAM(6), PARAM(7),
                                   t_mod, i_mod, 0, 1, xm);

  // 4) qkv GEMM
  k_gemm<0><<<dim3(3 * HS / 128, LQ / 128), 256, 0, stream>>>(
      xm, HS, 3 * HS, qkvT0, qkvT1, PARAM(25), PARAM(9),
      nullptr, nullptr, nullptr, nullptr, y, y + (size_t)LT * 3 * HS);

  // 5) RMS + RoPE ; V transpose
  k_qkv_post<<<NH * LQ / 4, 256, 0, stream>>>(y, pe, PARAM(26), PARAM(27), PARAM(10), PARAM(11),
                                              qh, kh);
  k_vtrans<<<dim3(LQ / 32, NH * 4), 256, 0, stream>>>(y, vT);

  // 6) attention (KV-split x4, LDS-staged K/V) + combine
  k_attn<<<NH * SPLIT * 40, 256, 0, stream>>>(qh, kh, vT, Op, ml);
  k_attn_combine<<<NH * LQ / 4, 256, 0, stream>>>(Op, ml, attnb);

  // 7) proj GEMM + gated residual
  k_gemm<1><<<dim3(HS / 128, LQ / 128), 256, 0, stream>>>(
      attnb, HS, HS, projT0, projT1, PARAM(29), PARAM(13),
      t_mod + 2 * HS, i_mod + 2 * HS, txt, img, x2, x2 + (size_t)LT * HS);

  // 8) LN2 + modulate
  k_ln_mod<<<LQ, 256, 0, stream>>>(x2, x2 + (size_t)LT * HS, PARAM(30), PARAM(31), PARAM(14),
                                   PARAM(15), t_mod, i_mod, 3, 4, xm2);

  // 9) MLP1 + gelu
  k_gemm<2><<<dim3(MLP_D / 128, LQ / 128), 256, 0, stream>>>(
      xm2, HS, MLP_D, mlp1T0, mlp1T1, PARAM(33), PARAM(17),
      nullptr, nullptr, nullptr, nullptr, h, h + (size_t)LT * MLP_D);

  // 10) MLP2 + gated residual -> d_out (img first)
  float* out_img = (float*)d_out;
  float* out_txt = (float*)d_out + (size_t)LI * HS;
  k_gemm<3><<<dim3(HS / 128, LQ / 128), 256, 0, stream>>>(
      h, MLP_D, HS, mlp2T0, mlp2T1, PARAM(35), PARAM(19),
      t_mod + 5 * HS, i_mod + 5 * HS, x2, x2 + (size_t)LT * HS, out_txt, out_img);
}

// Round 4
// 874.109 us; speedup vs baseline: 1.3516x; 1.0673x over previous
//
#include <hip/hip_runtime.h>
#include <hip/hip_bf16.h>
#include <math.h>

typedef __bf16 bf16;
typedef __bf16 bf16x2 __attribute__((ext_vector_type(2)));
typedef __bf16 bf16x8 __attribute__((ext_vector_type(8)));
typedef float f32x4 __attribute__((ext_vector_type(4)));

#define HS 2048
#define NH 16
#define HD 128
#define LT 512
#define LI 2048
#define LQ 2560
#define MLP_D 8192
#define SPLIT 4
#define KVS (LQ / SPLIT)  // 640 kv per split
#define KVBLK 32
#define NTILES (KVS / KVBLK)  // 20

__device__ __forceinline__ f32x4 mfma16(bf16x8 a, bf16x8 b, f32x4 c) {
  return __builtin_amdgcn_mfma_f32_16x16x32_bf16(a, b, c, 0, 0, 0);
}

// async global->LDS, 16B per lane; lds dest must be wave-uniform base (+lane*16 by HW)
__device__ __forceinline__ void gl_lds16(const bf16* g, bf16* l) {
  __builtin_amdgcn_global_load_lds((const __attribute__((address_space(1))) void*)g,
                                   (__attribute__((address_space(3))) void*)l, 16, 0, 0);
}

// ---------------- silu(vec) ----------------
__global__ void k_silu(const float* __restrict__ v, float* __restrict__ s) {
  int i = blockIdx.x * 256 + threadIdx.x;
  float x = v[i];
  s[i] = x / (1.f + expf(-x));
}

// ---------------- mod GEMV: silu(vec) @ mod_w, 2-pass (deterministic) ----------------
__global__ __launch_bounds__(256) void k_mod_partial(
    const float* __restrict__ s, const float* __restrict__ w_txt,
    const float* __restrict__ w_img, float* __restrict__ part) {
  int strm = blockIdx.x / 48;
  int n = (blockIdx.x % 48) * 256 + threadIdx.x;
  const float* w = strm ? w_img : w_txt;
  int k0 = blockIdx.y * 256;
  __shared__ float sl[256];
  sl[threadIdx.x] = s[k0 + threadIdx.x];
  __syncthreads();
  float acc = 0.f;
  for (int k = 0; k < 256; k++)
    acc += sl[k] * w[(size_t)(k0 + k) * 12288 + n];
  part[((size_t)blockIdx.y * 2 + strm) * 12288 + n] = acc;
}

__global__ __launch_bounds__(256) void k_mod_reduce(
    const float* __restrict__ part, const float* __restrict__ b_txt,
    const float* __restrict__ b_img, float* __restrict__ mod) {
  int strm = blockIdx.x / 48;
  int n = (blockIdx.x % 48) * 256 + threadIdx.x;
  float acc = strm ? b_img[n] : b_txt[n];
  for (int kc = 0; kc < 8; kc++)
    acc += part[((size_t)kc * 2 + strm) * 12288 + n];
  mod[(size_t)strm * 12288 + n] = acc;
}

// ---------------- weight transpose + fp32->bf16 : src[R][C] -> dst[C][R] ----------------
__global__ __launch_bounds__(256) void k_transpose_cvt(
    const float* __restrict__ src, bf16* __restrict__ dst, int R, int C) {
  __shared__ float t[32][33];
  int tx = threadIdx.x & 31, ty = threadIdx.x >> 5;
  int c0 = blockIdx.x * 32, r0 = blockIdx.y * 32;
  for (int i = 0; i < 32; i += 8)
    t[ty + i][tx] = src[(size_t)(r0 + ty + i) * C + c0 + tx];
  __syncthreads();
  for (int i = 0; i < 32; i += 8)
    dst[(size_t)(c0 + ty + i) * R + r0 + tx] = (bf16)t[tx][ty + i];
}

// ---------------- LayerNorm + modulate -> bf16 ----------------
__global__ __launch_bounds__(256) void k_ln_mod(
    const float* __restrict__ x0, const float* __restrict__ x1,
    const float* __restrict__ ls0, const float* __restrict__ lb0,
    const float* __restrict__ ls1, const float* __restrict__ lb1,
    const float* __restrict__ mod0, const float* __restrict__ mod1,
    int shidx, int scidx, bf16* __restrict__ out) {
  int r = blockIdx.x;
  int strm = r >= LT;
  const float* x = strm ? (x1 + (size_t)(r - LT) * HS) : (x0 + (size_t)r * HS);
  const float* ls = strm ? ls1 : ls0;
  const float* lb = strm ? lb1 : lb0;
  const float* md = strm ? mod1 : mod0;
  const float* sh = md + (size_t)shidx * HS;
  const float* sc = md + (size_t)scidx * HS;
  int t = threadIdx.x;
  float4 a = ((const float4*)x)[t * 2];
  float4 b = ((const float4*)x)[t * 2 + 1];
  float xv[8] = {a.x, a.y, a.z, a.w, b.x, b.y, b.z, b.w};
  float sum = 0.f, sq = 0.f;
#pragma unroll
  for (int j = 0; j < 8; j++) { sum += xv[j]; sq += xv[j] * xv[j]; }
#pragma unroll
  for (int m = 32; m; m >>= 1) { sum += __shfl_xor(sum, m); sq += __shfl_xor(sq, m); }
  __shared__ float red[8];
  int lane = t & 63, wid = t >> 6;
  if (!lane) { red[wid] = sum; red[wid + 4] = sq; }
  __syncthreads();
  float ts = red[0] + red[1] + red[2] + red[3];
  float tq = red[4] + red[5] + red[6] + red[7];
  float mean = ts * (1.f / HS);
  float var = tq * (1.f / HS) - mean * mean;
  float inv = rsqrtf(var + 1e-6f);
  int c0 = t * 8;
  bf16x8 ov;
#pragma unroll
  for (int j = 0; j < 8; j++) {
    int c = c0 + j;
    float v = ((xv[j] - mean) * inv * ls[c] + lb[c]) * (1.f + sc[c]) + sh[c];
    ov[j] = (bf16)v;
  }
  *(bf16x8*)(out + (size_t)r * HS + c0) = ov;
}

// ---------------- GEMM: A[2560][K] bf16 @ BT[N][K] bf16, dual-stream weights ----------------
// MODE 0: out bf16 = acc+bias (qkv) ; 2: bf16 gelu(acc+bias) (mlp1)
// MODE 4: f32 partial (split-K over blockIdx.z, Ksz cols each), no bias
template <int MODE>
__global__ __launch_bounds__(256) void k_gemm(
    const bf16* __restrict__ A, int K, int N, int Ksz,
    const bf16* __restrict__ BT0, const bf16* __restrict__ BT1,
    const float* __restrict__ bias0, const float* __restrict__ bias1,
    void* __restrict__ out0, void* __restrict__ out1) {
  __shared__ bf16 As[128 * 32];
  __shared__ bf16 Bs[128 * 32];
  int tid = threadIdx.x;
  int bn = blockIdx.x, bm = blockIdx.y;
  int strm = (bm * 128) >= LT;
  int lm = bm * 128 - strm * LT;
  const bf16* BT = strm ? BT1 : BT0;
  int lane = tid & 63, wid = tid >> 6;
  int wr = wid >> 1, wc = wid & 1;
  int sr = tid >> 2, sc8 = (tid & 3) * 8;
  const bf16* Ag = A + (size_t)(bm * 128 + sr) * K + sc8;
  const bf16* Bg = BT + (size_t)(bn * 128 + sr) * K + sc8;
  bf16* As_dst = As + wid * 512;
  bf16* Bs_dst = Bs + wid * 512;
  int kbeg = MODE == 4 ? blockIdx.z * Ksz : 0;
  f32x4 acc[4][4] = {};
  for (int k0 = kbeg; k0 < kbeg + Ksz; k0 += 32) {
    __syncthreads();
    gl_lds16(Ag + k0, As_dst);
    gl_lds16(Ag + (size_t)64 * K + k0, As_dst + 2048);
    gl_lds16(Bg + k0, Bs_dst);
    gl_lds16(Bg + (size_t)64 * K + k0, Bs_dst + 2048);
    __syncthreads();
    bf16x8 af[4], bfr[4];
    int r16 = lane & 15, kc8 = (lane >> 4) * 8;
#pragma unroll
    for (int m = 0; m < 4; m++) af[m] = *(const bf16x8*)&As[(wr * 64 + m * 16 + r16) * 32 + kc8];
#pragma unroll
    for (int n = 0; n < 4; n++) bfr[n] = *(const bf16x8*)&Bs[(wc * 64 + n * 16 + r16) * 32 + kc8];
#pragma unroll
    for (int m = 0; m < 4; m++)
#pragma unroll
      for (int n = 0; n < 4; n++)
        acc[m][n] = mfma16(af[m], bfr[n], acc[m][n]);
  }
  int col = lane & 15, rb = (lane >> 4) * 4;
  const float* bias = strm ? bias1 : bias0;
  float* part = MODE == 4 ? (float*)out0 + (size_t)blockIdx.z * LQ * N : nullptr;
#pragma unroll
  for (int m = 0; m < 4; m++) {
#pragma unroll
    for (int n = 0; n < 4; n++) {
      int gn = bn * 128 + wc * 64 + n * 16 + col;
      float bv = MODE == 4 ? 0.f : bias[gn];
#pragma unroll
      for (int r = 0; r < 4; r++) {
        int lr = wr * 64 + m * 16 + rb + r;
        float v = acc[m][n][r] + bv;
        if (MODE == 0) {
          ((bf16*)(strm ? out1 : out0))[(size_t)(lm + lr) * N + gn] = (bf16)v;
        } else if (MODE == 2) {
          float g = 0.5f * v * (1.f + tanhf(0.7978845608028654f * (v + 0.044715f * v * v * v)));
          ((bf16*)(strm ? out1 : out0))[(size_t)(lm + lr) * N + gn] = (bf16)g;
        } else {
          part[(size_t)(bm * 128 + lr) * N + gn] = v;
        }
      }
    }
  }
}

// ---------------- split-K combine: out = res + gate*(sum(part)+bias), f32 ----------------
template <int S>
__global__ __launch_bounds__(256) void k_skcomb(
    const float* __restrict__ part, int N,
    const float* __restrict__ bias0, const float* __restrict__ bias1,
    const float* __restrict__ gate0, const float* __restrict__ gate1,
    const float* __restrict__ res0, const float* __restrict__ res1,
    float* __restrict__ out0, float* __restrict__ out1) {
  int gid = blockIdx.x * 256 + threadIdx.x;
  int nv = N >> 2;
  int row = gid / nv, cv = gid - row * nv;
  int strm = row >= LT;
  int lrow = row - strm * LT;
  const float* bias = strm ? bias1 : bias0;
  const float* gate = strm ? gate1 : gate0;
  const float* res = strm ? res1 : res0;
  float* out = strm ? out1 : out0;
  int c = cv * 4;
  float4 acc = *(const float4*)(bias + c);
#pragma unroll
  for (int s = 0; s < S; s++) {
    float4 p = *(const float4*)(part + ((size_t)s * LQ + row) * N + c);
    acc.x += p.x; acc.y += p.y; acc.z += p.z; acc.w += p.w;
  }
  float4 g = *(const float4*)(gate + c);
  float4 r = *(const float4*)(res + (size_t)lrow * N + c);
  float4 o = {r.x + g.x * acc.x, r.y + g.y * acc.y, r.z + g.z * acc.z, r.w + g.w * acc.w};
  *(float4*)(out + (size_t)lrow * N + c) = o;
}

// ---------------- qkv post: RMS norm (q,k) + RoPE + scale ----------------
__global__ __launch_bounds__(256) void k_qkv_post(
    const bf16* __restrict__ y, const float* __restrict__ pe,
    const float* __restrict__ qn0, const float* __restrict__ kn0,
    const float* __restrict__ qn1, const float* __restrict__ kn1,
    bf16* __restrict__ qh, bf16* __restrict__ kh) {
  int wv = (int)((blockIdx.x * 256 + threadIdx.x) >> 6);
  int lane = threadIdx.x & 63;
  int head = wv / LQ, l = wv - head * LQ;
  const bf16* yr = y + (size_t)l * (3 * HS) + head * HD;
  float q0 = (float)yr[2 * lane], q1 = (float)yr[2 * lane + 1];
  float k0 = (float)yr[HS + 2 * lane], k1 = (float)yr[HS + 2 * lane + 1];
  float sqs = q0 * q0 + q1 * q1, sks = k0 * k0 + k1 * k1;
#pragma unroll
  for (int m = 1; m < 64; m <<= 1) { sqs += __shfl_xor(sqs, m); sks += __shfl_xor(sks, m); }
  float rq = rsqrtf(sqs * (1.f / HD) + 1e-6f);
  float rk = rsqrtf(sks * (1.f / HD) + 1e-6f);
  int strm = l >= LT;
  const float* qn = strm ? qn1 : qn0;
  const float* kn = strm ? kn1 : kn0;
  float e0 = q0 * rq * qn[2 * lane], e1 = q1 * rq * qn[2 * lane + 1];
  float f0 = k0 * rk * kn[2 * lane], f1 = k1 * rk * kn[2 * lane + 1];
  float4 p = *(const float4*)(pe + ((size_t)l * 64 + lane) * 4);
  const float scl = 0.08838834764831845f;  // 128^-0.5 folded into q
  size_t qi = ((size_t)head * LQ + l) * HD + 2 * lane;
  bf16x2 qv = {(bf16)((p.x * e0 + p.y * e1) * scl), (bf16)((p.z * e0 + p.w * e1) * scl)};
  bf16x2 kv = {(bf16)(p.x * f0 + p.y * f1), (bf16)(p.z * f0 + p.w * f1)};
  *(bf16x2*)(qh + qi) = qv;
  *(bf16x2*)(kh + qi) = kv;
}

// ---------------- V transpose: y v-part [l][head*HD+d] -> vT [head][d][l] ----------------
__global__ __launch_bounds__(256) void k_vtrans(const bf16* __restrict__ y,
                                                bf16* __restrict__ vT) {
  __shared__ bf16 t[32][34];
  int head = blockIdx.y >> 2, dt = blockIdx.y & 3;
  int tx = threadIdx.x & 31, ty = threadIdx.x >> 5;
  int l0 = blockIdx.x * 32, d0 = dt * 32;
  for (int i = 0; i < 32; i += 8)
    t[ty + i][tx] = y[(size_t)(l0 + ty + i) * (3 * HS) + 2 * HS + head * HD + d0 + tx];
  __syncthreads();
  for (int i = 0; i < 32; i += 8)
    vT[(size_t)(head * HD + d0 + ty + i) * LQ + l0 + tx] = t[tx][ty + i];
}

// ---------------- flash attention: KV-split x4, K/V staged in LDS (shared by 4 waves) --------
__global__ __launch_bounds__(256, 5) void k_attn(
    const bf16* __restrict__ Q, const bf16* __restrict__ Kh,
    const bf16* __restrict__ VT, bf16* __restrict__ Op, float* __restrict__ ml) {
  __shared__ bf16 Ks[KVBLK * 128];   // [kv][hd], 256B rows, content swizzled
  __shared__ bf16 Vs[128 * KVBLK];   // V^T [d][kv], 64B rows, linear
  __shared__ bf16 P[4][16 * 34];     // per-wave [16 q][32 kv pad 34]
  int tid = threadIdx.x, lane = tid & 63, w = tid >> 6;
  int b = blockIdx.x;
  int qb = b % 40;
  int split = (b / 40) % SPLIT;
  int head = b / (40 * SPLIT);
  int qr = qb * 64 + w * 16;
  int r16 = lane & 15, g = lane >> 4;
  const bf16* qp = Q + ((size_t)head * LQ + qr + r16) * HD + g * 8;
  bf16x8 qf[4];
#pragma unroll
  for (int c = 0; c < 4; c++) qf[c] = *(const bf16x8*)(qp + c * 32);
  f32x4 O[8] = {};
  float mr[4], lr[4];
#pragma unroll
  for (int i = 0; i < 4; i++) { mr[i] = -1e30f; lr[i] = 0.f; }
  bf16* pl = &P[w][0];
  const bf16* kbase = Kh + ((size_t)head * LQ + split * KVS) * HD;
  const bf16* vbase = VT + (size_t)head * HD * LQ + split * KVS;
  int krow0 = w * 8 + (lane >> 4);
  int kslot = lane & 15;
  int vrow0 = w * 32 + (lane >> 2);
  int vcol = (lane & 3) * 8;
  for (int t = 0; t < NTILES; t++) {
    int kv0 = t * KVBLK;
#pragma unroll
    for (int i = 0; i < 2; i++) {
      int krow = krow0 + i * 4;
      gl_lds16(kbase + (size_t)(kv0 + krow) * HD + ((kslot ^ (krow & 7)) << 3),
               Ks + (w * 8 + i * 4) * 128);
      int vrow = vrow0 + i * 16;
      gl_lds16(vbase + (size_t)vrow * LQ + kv0 + vcol,
               Vs + (w * 32 + i * 16) * KVBLK);
    }
    __syncthreads();
    f32x4 S0 = {}, S1 = {};
    int sw = (r16 & 7);
#pragma unroll
    for (int c = 0; c < 4; c++) {
      int slot = ((4 * c + g) ^ sw) << 3;
      bf16x8 ka = *(const bf16x8*)&Ks[r16 * 128 + slot];
      bf16x8 kb = *(const bf16x8*)&Ks[(16 + r16) * 128 + slot];
      S0 = mfma16(qf[c], ka, S0);
      S1 = mfma16(qf[c], kb, S1);
    }
    float alpha[4];
#pragma unroll
    for (int i = 0; i < 4; i++) {
      float mx = fmaxf(S0[i], S1[i]);
#pragma unroll
      for (int m = 8; m; m >>= 1) mx = fmaxf(mx, __shfl_xor(mx, m));
      float mn = fmaxf(mr[i], mx);
      float p0 = __expf(S0[i] - mn), p1 = __expf(S1[i] - mn);
      float rs = p0 + p1;
#pragma unroll
      for (int m = 8; m; m >>= 1) rs += __shfl_xor(rs, m);
      alpha[i] = __expf(mr[i] - mn);
      lr[i] = lr[i] * alpha[i] + rs;
      mr[i] = mn;
      pl[(4 * g + i) * 34 + r16] = (bf16)p0;
      pl[(4 * g + i) * 34 + 16 + r16] = (bf16)p1;
    }
    bf16x8 pf = *(const bf16x8*)&pl[r16 * 34 + g * 8];
#pragma unroll
    for (int n = 0; n < 8; n++) {
      f32x4 o = O[n];
#pragma unroll
      for (int i = 0; i < 4; i++) o[i] *= alpha[i];
      bf16x8 vf = *(const bf16x8*)&Vs[(n * 16 + r16) * KVBLK + g * 8];
      O[n] = mfma16(pf, vf, o);
    }
    __syncthreads();
  }
  const int NL = NH * LQ;
  bf16* op = Op + (size_t)split * NL * HD;
#pragma unroll
  for (int n = 0; n < 8; n++)
#pragma unroll
    for (int i = 0; i < 4; i++)
      op[((size_t)head * LQ + qr + 4 * g + i) * HD + n * 16 + r16] = (bf16)O[n][i];
  if (r16 == 0) {
#pragma unroll
    for (int i = 0; i < 4; i++) {
      int idx = head * LQ + qr + 4 * g + i;
      ml[(size_t)(split * 2 + 0) * NL + idx] = mr[i];
      ml[(size_t)(split * 2 + 1) * NL + idx] = lr[i];
    }
  }
}

// ---------------- combine SPLIT KV-parts -> attnb [l][head*HD+d] bf16 ----------------
__global__ __launch_bounds__(256) void k_attn_combine(
    const bf16* __restrict__ Op, const float* __restrict__ ml, bf16* __restrict__ out) {
  int lane = threadIdx.x & 63, w = threadIdx.x >> 6;
  int row = blockIdx.x * 4 + w;  // head*LQ + l
  int head = row / LQ, l = row - head * LQ;
  const int NL = NH * LQ;
  float ms[SPLIT], ls[SPLIT], m = -1e30f;
#pragma unroll
  for (int s = 0; s < SPLIT; s++) {
    ms[s] = ml[(size_t)(s * 2) * NL + row];
    ls[s] = ml[(size_t)(s * 2 + 1) * NL + row];
    m = fmaxf(m, ms[s]);
  }
  float wsum = 0.f, wgt[SPLIT];
#pragma unroll
  for (int s = 0; s < SPLIT; s++) { wgt[s] = __expf(ms[s] - m); wsum += wgt[s] * ls[s]; }
  float inv = 1.f / wsum;
  size_t oi = (size_t)row * HD + 2 * lane;
  float a0 = 0.f, a1 = 0.f;
#pragma unroll
  for (int s = 0; s < SPLIT; s++) {
    bf16x2 v = *(const bf16x2*)(Op + (size_t)s * NL * HD + oi);
    a0 += wgt[s] * (float)v[0];
    a1 += wgt[s] * (float)v[1];
  }
  bf16x2 ov = {(bf16)(a0 * inv), (bf16)(a1 * inv)};
  *(bf16x2*)(out + (size_t)l * HS + head * HD + 2 * lane) = ov;
}

// ---------------- launch ----------------
extern "C" void kernel_launch(void* const* d_in, const int* in_sizes, int n_in,
                              void* d_out, int out_size, void* d_ws, size_t ws_size,
                              hipStream_t stream) {
  const float* img = (const float*)d_in[0];
  const float* txt = (const float*)d_in[1];
  const float* vec = (const float*)d_in[2];
  const float* pe = (const float*)d_in[3];
#define PARAM(i) ((const float*)d_in[i])

  char* ws = (char*)d_ws;
  size_t off = 0;
  auto alloc = [&](size_t b) { void* p = ws + off; off += (b + 255) & ~(size_t)255; return p; };
  float* silu_s = (float*)alloc((size_t)HS * 4);
  float* mpart = (float*)alloc((size_t)8 * 2 * 12288 * 4);
  float* mod = (float*)alloc((size_t)2 * 6 * HS * 4);
  bf16* qkvT0 = (bf16*)alloc((size_t)3 * HS * HS * 2);
  bf16* qkvT1 = (bf16*)alloc((size_t)3 * HS * HS * 2);
  bf16* projT0 = (bf16*)alloc((size_t)HS * HS * 2);
  bf16* projT1 = (bf16*)alloc((size_t)HS * HS * 2);
  bf16* mlp1T0 = (bf16*)alloc((size_t)MLP_D * HS * 2);
  bf16* mlp1T1 = (bf16*)alloc((size_t)MLP_D * HS * 2);
  bf16* mlp2T0 = (bf16*)alloc((size_t)HS * MLP_D * 2);
  bf16* mlp2T1 = (bf16*)alloc((size_t)HS * MLP_D * 2);
  bf16* xm = (bf16*)alloc((size_t)LQ * HS * 2);
  bf16* y = (bf16*)alloc((size_t)LQ * 3 * HS * 2);
  bf16* qh = (bf16*)alloc((size_t)NH * LQ * HD * 2);
  bf16* kh = (bf16*)alloc((size_t)NH * LQ * HD * 2);
  bf16* vT = (bf16*)alloc((size_t)NH * HD * LQ * 2);
  bf16* attnb = (bf16*)alloc((size_t)LQ * HS * 2);
  float* x2 = (float*)alloc((size_t)LQ * HS * 4);
  bf16* xm2 = (bf16*)alloc((size_t)LQ * HS * 2);
  bf16* h = (bf16*)alloc((size_t)LQ * MLP_D * 2);
  float* ml = (float*)alloc((size_t)2 * SPLIT * NH * LQ * 4);
  // aliases (regions dead at time of use):
  bf16* Op = h;                 // attn partials (4 x 10.5MB) in h, dead until step 9
  float* skpart = (float*)xm;   // split-K partials: proj 2x21MB fits xm+y (42MB);
                                // mlp2 4x21MB fits xm..attnb (exactly 84MB)
  (void)ws_size; (void)in_sizes; (void)n_in; (void)out_size;

  const float* t_mod = mod;
  const float* i_mod = mod + 6 * HS;

  // 1) modulation vectors
  k_silu<<<HS / 256, 256, 0, stream>>>(vec, silu_s);
  k_mod_partial<<<dim3(96, 8), 256, 0, stream>>>(silu_s, PARAM(20), PARAM(4), mpart);
  k_mod_reduce<<<96, 256, 0, stream>>>(mpart, PARAM(21), PARAM(5), mod);

  // 2) weight transpose+cvt
  k_transpose_cvt<<<dim3(3 * HS / 32, HS / 32), 256, 0, stream>>>(PARAM(24), qkvT0, HS, 3 * HS);
  k_transpose_cvt<<<dim3(3 * HS / 32, HS / 32), 256, 0, stream>>>(PARAM(8), qkvT1, HS, 3 * HS);
  k_transpose_cvt<<<dim3(HS / 32, HS / 32), 256, 0, stream>>>(PARAM(28), projT0, HS, HS);
  k_transpose_cvt<<<dim3(HS / 32, HS / 32), 256, 0, stream>>>(PARAM(12), projT1, HS, HS);
  k_transpose_cvt<<<dim3(MLP_D / 32, HS / 32), 256, 0, stream>>>(PARAM(32), mlp1T0, HS, MLP_D);
  k_transpose_cvt<<<dim3(MLP_D / 32, HS / 32), 256, 0, stream>>>(PARAM(16), mlp1T1, HS, MLP_D);
  k_transpose_cvt<<<dim3(HS / 32, MLP_D / 32), 256, 0, stream>>>(PARAM(34), mlp2T0, MLP_D, HS);
  k_transpose_cvt<<<dim3(HS / 32, MLP_D / 32), 256, 0, stream>>>(PARAM(18), mlp2T1, MLP_D, HS);

  // 3) LN1 + modulate
  k_ln_mod<<<LQ, 256, 0, stream>>>(txt, img, PARAM(22), PARAM(23), PARAM(6), PARAM(7),
                                   t_mod, i_mod, 0, 1, xm);

  // 4) qkv GEMM
  k_gemm<0><<<dim3(3 * HS / 128, LQ / 128), 256, 0, stream>>>(
      xm, HS, 3 * HS, HS, qkvT0, qkvT1, PARAM(25), PARAM(9), y, y + (size_t)LT * 3 * HS);

  // 5) RMS + RoPE ; V transpose
  k_qkv_post<<<NH * LQ / 4, 256, 0, stream>>>(y, pe, PARAM(26), PARAM(27), PARAM(10), PARAM(11),
                                              qh, kh);
  k_vtrans<<<dim3(LQ / 32, NH * 4), 256, 0, stream>>>(y, vT);

  // 6) attention (KV-split x4, LDS-staged K/V) + combine
  k_attn<<<NH * SPLIT * 40, 256, 0, stream>>>(qh, kh, vT, Op, ml);
  k_attn_combine<<<NH * LQ / 4, 256, 0, stream>>>(Op, ml, attnb);

  // 7) proj GEMM split-K x2 (f32 partials alias xm+y) + combine -> x2
  k_gemm<4><<<dim3(HS / 128, LQ / 128, 2), 256, 0, stream>>>(
      attnb, HS, HS, HS / 2, projT0, projT1, nullptr, nullptr, skpart, nullptr);
  k_skcomb<2><<<LQ * HS / 4 / 256, 256, 0, stream>>>(
      skpart, HS, PARAM(29), PARAM(13), t_mod + 2 * HS, i_mod + 2 * HS, txt, img,
      x2, x2 + (size_t)LT * HS);

  // 8) LN2 + modulate
  k_ln_mod<<<LQ, 256, 0, stream>>>(x2, x2 + (size_t)LT * HS, PARAM(30), PARAM(31), PARAM(14),
                                   PARAM(15), t_mod, i_mod, 3, 4, xm2);

  // 9) MLP1 + gelu
  k_gemm<2><<<dim3(MLP_D / 128, LQ / 128), 256, 0, stream>>>(
      xm2, HS, MLP_D, HS, mlp1T0, mlp1T1, PARAM(33), PARAM(17), h, h + (size_t)LT * MLP_D);

  // 10) MLP2 split-K x4 (f32 partials alias xm..attnb) + combine -> d_out (img first)
  float* out_img = (float*)d_out;
  float* out_txt = (float*)d_out + (size_t)LI * HS;
  k_gemm<4><<<dim3(HS / 128, LQ / 128, 4), 256, 0, stream>>>(
      h, MLP_D, HS, MLP_D / 4, mlp2T0, mlp2T1, nullptr, nullptr, skpart, nullptr);
  k_skcomb<4><<<LQ * HS / 4 / 256, 256, 0, stream>>>(
      skpart, HS, PARAM(35), PARAM(19), t_mod + 5 * HS, i_mod + 5 * HS, x2,
      x2 + (size_t)LT * HS, out_txt, out_img);
}

// Round 5
// 860.393 us; speedup vs baseline: 1.3731x; 1.0159x over previous
//
#include <hip/hip_runtime.h>
#include <hip/hip_bf16.h>
#include <math.h>

typedef __bf16 bf16;
typedef __bf16 bf16x2 __attribute__((ext_vector_type(2)));
typedef __bf16 bf16x8 __attribute__((ext_vector_type(8)));
typedef float f32x4 __attribute__((ext_vector_type(4)));

#define HS 2048
#define NH 16
#define HD 128
#define LT 512
#define LI 2048
#define LQ 2560
#define MLP_D 8192
#define SPLIT 4
#define KVS (LQ / SPLIT)  // 640 kv per split
#define KVBLK 32
#define NTILES (KVS / KVBLK)  // 20

__device__ __forceinline__ f32x4 mfma16(bf16x8 a, bf16x8 b, f32x4 c) {
  return __builtin_amdgcn_mfma_f32_16x16x32_bf16(a, b, c, 0, 0, 0);
}

// async global->LDS, 16B per lane; lds dest must be wave-uniform base (+lane*16 by HW)
__device__ __forceinline__ void gl_lds16(const bf16* g, bf16* l) {
  __builtin_amdgcn_global_load_lds((const __attribute__((address_space(1))) void*)g,
                                   (__attribute__((address_space(3))) void*)l, 16, 0, 0);
}

// ---------------- silu(vec) ----------------
__global__ void k_silu(const float* __restrict__ v, float* __restrict__ s) {
  int i = blockIdx.x * 256 + threadIdx.x;
  float x = v[i];
  s[i] = x / (1.f + expf(-x));
}

// ---------------- mod GEMV: silu(vec) @ mod_w, 2-pass (deterministic) ----------------
__global__ __launch_bounds__(256) void k_mod_partial(
    const float* __restrict__ s, const float* __restrict__ w_txt,
    const float* __restrict__ w_img, float* __restrict__ part) {
  int strm = blockIdx.x / 48;
  int n = (blockIdx.x % 48) * 256 + threadIdx.x;
  const float* w = strm ? w_img : w_txt;
  int k0 = blockIdx.y * 256;
  __shared__ float sl[256];
  sl[threadIdx.x] = s[k0 + threadIdx.x];
  __syncthreads();
  float acc = 0.f;
  for (int k = 0; k < 256; k++)
    acc += sl[k] * w[(size_t)(k0 + k) * 12288 + n];
  part[((size_t)blockIdx.y * 2 + strm) * 12288 + n] = acc;
}

__global__ __launch_bounds__(256) void k_mod_reduce(
    const float* __restrict__ part, const float* __restrict__ b_txt,
    const float* __restrict__ b_img, float* __restrict__ mod) {
  int strm = blockIdx.x / 48;
  int n = (blockIdx.x % 48) * 256 + threadIdx.x;
  float acc = strm ? b_img[n] : b_txt[n];
  for (int kc = 0; kc < 8; kc++)
    acc += part[((size_t)kc * 2 + strm) * 12288 + n];
  mod[(size_t)strm * 12288 + n] = acc;
}

// ---------------- weight transpose + fp32->bf16 : src[R][C] -> dst[C][R] ----------------
// 64x64 tile; reads coalesced f32 rows, writes coalesced bf16x8 (16B/lane) rows of dst.
__global__ __launch_bounds__(256) void k_transpose_cvt(
    const float* __restrict__ src, bf16* __restrict__ dst, int R, int C) {
  __shared__ float t[64][65];
  int tx = threadIdx.x & 63, ty = threadIdx.x >> 6;
  int c0 = blockIdx.x * 64, r0 = blockIdx.y * 64;
  for (int i = 0; i < 64; i += 4)
    t[ty + i][tx] = src[(size_t)(r0 + ty + i) * C + c0 + tx];
  __syncthreads();
#pragma unroll
  for (int j = 0; j < 2; j++) {
    int c = (threadIdx.x >> 3) + j * 32;
    int gg = (threadIdx.x & 7) * 8;
    bf16x8 ov;
#pragma unroll
    for (int k = 0; k < 8; k++) ov[k] = (bf16)t[gg + k][c];
    *(bf16x8*)(dst + (size_t)(c0 + c) * R + r0 + gg) = ov;
  }
}

// ---------------- LayerNorm + modulate -> bf16 ----------------
__global__ __launch_bounds__(256) void k_ln_mod(
    const float* __restrict__ x0, const float* __restrict__ x1,
    const float* __restrict__ ls0, const float* __restrict__ lb0,
    const float* __restrict__ ls1, const float* __restrict__ lb1,
    const float* __restrict__ mod0, const float* __restrict__ mod1,
    int shidx, int scidx, bf16* __restrict__ out) {
  int r = blockIdx.x;
  int strm = r >= LT;
  const float* x = strm ? (x1 + (size_t)(r - LT) * HS) : (x0 + (size_t)r * HS);
  const float* ls = strm ? ls1 : ls0;
  const float* lb = strm ? lb1 : lb0;
  const float* md = strm ? mod1 : mod0;
  const float* sh = md + (size_t)shidx * HS;
  const float* sc = md + (size_t)scidx * HS;
  int t = threadIdx.x;
  float4 a = ((const float4*)x)[t * 2];
  float4 b = ((const float4*)x)[t * 2 + 1];
  float xv[8] = {a.x, a.y, a.z, a.w, b.x, b.y, b.z, b.w};
  float sum = 0.f, sq = 0.f;
#pragma unroll
  for (int j = 0; j < 8; j++) { sum += xv[j]; sq += xv[j] * xv[j]; }
#pragma unroll
  for (int m = 32; m; m >>= 1) { sum += __shfl_xor(sum, m); sq += __shfl_xor(sq, m); }
  __shared__ float red[8];
  int lane = t & 63, wid = t >> 6;
  if (!lane) { red[wid] = sum; red[wid + 4] = sq; }
  __syncthreads();
  float ts = red[0] + red[1] + red[2] + red[3];
  float tq = red[4] + red[5] + red[6] + red[7];
  float mean = ts * (1.f / HS);
  float var = tq * (1.f / HS) - mean * mean;
  float inv = rsqrtf(var + 1e-6f);
  int c0 = t * 8;
  bf16x8 ov;
#pragma unroll
  for (int j = 0; j < 8; j++) {
    int c = c0 + j;
    float v = ((xv[j] - mean) * inv * ls[c] + lb[c]) * (1.f + sc[c]) + sh[c];
    ov[j] = (bf16)v;
  }
  *(bf16x8*)(out + (size_t)r * HS + c0) = ov;
}

// ---------------- GEMM: A[2560][K] bf16 @ BT[N][K] bf16, dual-stream weights ----------------
// MODE 0: out bf16 = acc+bias (qkv) ; 2: bf16 gelu(acc+bias) (mlp1)
// MODE 4: f32 partial (split-K over blockIdx.z, Ksz cols each), no bias
template <int MODE>
__global__ __launch_bounds__(256) void k_gemm(
    const bf16* __restrict__ A, int K, int N, int Ksz,
    const bf16* __restrict__ BT0, const bf16* __restrict__ BT1,
    const float* __restrict__ bias0, const float* __restrict__ bias1,
    void* __restrict__ out0, void* __restrict__ out1) {
  __shared__ bf16 As[128 * 32];
  __shared__ bf16 Bs[128 * 32];
  int tid = threadIdx.x;
  int bn = blockIdx.x, bm = blockIdx.y;
  int strm = (bm * 128) >= LT;
  int lm = bm * 128 - strm * LT;
  const bf16* BT = strm ? BT1 : BT0;
  int lane = tid & 63, wid = tid >> 6;
  int wr = wid >> 1, wc = wid & 1;
  int sr = tid >> 2, sc8 = (tid & 3) * 8;
  const bf16* Ag = A + (size_t)(bm * 128 + sr) * K + sc8;
  const bf16* Bg = BT + (size_t)(bn * 128 + sr) * K + sc8;
  bf16* As_dst = As + wid * 512;
  bf16* Bs_dst = Bs + wid * 512;
  int kbeg = MODE == 4 ? blockIdx.z * Ksz : 0;
  f32x4 acc[4][4] = {};
  for (int k0 = kbeg; k0 < kbeg + Ksz; k0 += 32) {
    __syncthreads();
    gl_lds16(Ag + k0, As_dst);
    gl_lds16(Ag + (size_t)64 * K + k0, As_dst + 2048);
    gl_lds16(Bg + k0, Bs_dst);
    gl_lds16(Bg + (size_t)64 * K + k0, Bs_dst + 2048);
    __syncthreads();
    bf16x8 af[4], bfr[4];
    int r16 = lane & 15, kc8 = (lane >> 4) * 8;
#pragma unroll
    for (int m = 0; m < 4; m++) af[m] = *(const bf16x8*)&As[(wr * 64 + m * 16 + r16) * 32 + kc8];
#pragma unroll
    for (int n = 0; n < 4; n++) bfr[n] = *(const bf16x8*)&Bs[(wc * 64 + n * 16 + r16) * 32 + kc8];
#pragma unroll
    for (int m = 0; m < 4; m++)
#pragma unroll
      for (int n = 0; n < 4; n++)
        acc[m][n] = mfma16(af[m], bfr[n], acc[m][n]);
  }
  int col = lane & 15, rb = (lane >> 4) * 4;
  const float* bias = strm ? bias1 : bias0;
  float* part = MODE == 4 ? (float*)out0 + (size_t)blockIdx.z * LQ * N : nullptr;
#pragma unroll
  for (int m = 0; m < 4; m++) {
#pragma unroll
    for (int n = 0; n < 4; n++) {
      int gn = bn * 128 + wc * 64 + n * 16 + col;
      float bv = MODE == 4 ? 0.f : bias[gn];
#pragma unroll
      for (int r = 0; r < 4; r++) {
        int lr = wr * 64 + m * 16 + rb + r;
        float v = acc[m][n][r] + bv;
        if (MODE == 0) {
          ((bf16*)(strm ? out1 : out0))[(size_t)(lm + lr) * N + gn] = (bf16)v;
        } else if (MODE == 2) {
          float g = 0.5f * v * (1.f + tanhf(0.7978845608028654f * (v + 0.044715f * v * v * v)));
          ((bf16*)(strm ? out1 : out0))[(size_t)(lm + lr) * N + gn] = (bf16)g;
        } else {
          part[(size_t)(bm * 128 + lr) * N + gn] = v;
        }
      }
    }
  }
}

// ---------------- split-K combine: out = res + gate*(sum(part)+bias), f32 ----------------
template <int S>
__global__ __launch_bounds__(256) void k_skcomb(
    const float* __restrict__ part, int N,
    const float* __restrict__ bias0, const float* __restrict__ bias1,
    const float* __restrict__ gate0, const float* __restrict__ gate1,
    const float* __restrict__ res0, const float* __restrict__ res1,
    float* __restrict__ out0, float* __restrict__ out1) {
  int gid = blockIdx.x * 256 + threadIdx.x;
  int nv = N >> 2;
  int row = gid / nv, cv = gid - row * nv;
  int strm = row >= LT;
  int lrow = row - strm * LT;
  const float* bias = strm ? bias1 : bias0;
  const float* gate = strm ? gate1 : gate0;
  const float* res = strm ? res1 : res0;
  float* out = strm ? out1 : out0;
  int c = cv * 4;
  float4 acc = *(const float4*)(bias + c);
#pragma unroll
  for (int s = 0; s < S; s++) {
    float4 p = *(const float4*)(part + ((size_t)s * LQ + row) * N + c);
    acc.x += p.x; acc.y += p.y; acc.z += p.z; acc.w += p.w;
  }
  float4 g = *(const float4*)(gate + c);
  float4 r = *(const float4*)(res + (size_t)lrow * N + c);
  float4 o = {r.x + g.x * acc.x, r.y + g.y * acc.y, r.z + g.z * acc.z, r.w + g.w * acc.w};
  *(float4*)(out + (size_t)lrow * N + c) = o;
}

// ---------------- qkv post: RMS norm (q,k) + RoPE + scale ----------------
__global__ __launch_bounds__(256) void k_qkv_post(
    const bf16* __restrict__ y, const float* __restrict__ pe,
    const float* __restrict__ qn0, const float* __restrict__ kn0,
    const float* __restrict__ qn1, const float* __restrict__ kn1,
    bf16* __restrict__ qh, bf16* __restrict__ kh) {
  int wv = (int)((blockIdx.x * 256 + threadIdx.x) >> 6);
  int lane = threadIdx.x & 63;
  int head = wv / LQ, l = wv - head * LQ;
  const bf16* yr = y + (size_t)l * (3 * HS) + head * HD;
  float q0 = (float)yr[2 * lane], q1 = (float)yr[2 * lane + 1];
  float k0 = (float)yr[HS + 2 * lane], k1 = (float)yr[HS + 2 * lane + 1];
  float sqs = q0 * q0 + q1 * q1, sks = k0 * k0 + k1 * k1;
#pragma unroll
  for (int m = 1; m < 64; m <<= 1) { sqs += __shfl_xor(sqs, m); sks += __shfl_xor(sks, m); }
  float rq = rsqrtf(sqs * (1.f / HD) + 1e-6f);
  float rk = rsqrtf(sks * (1.f / HD) + 1e-6f);
  int strm = l >= LT;
  const float* qn = strm ? qn1 : qn0;
  const float* kn = strm ? kn1 : kn0;
  float e0 = q0 * rq * qn[2 * lane], e1 = q1 * rq * qn[2 * lane + 1];
  float f0 = k0 * rk * kn[2 * lane], f1 = k1 * rk * kn[2 * lane + 1];
  float4 p = *(const float4*)(pe + ((size_t)l * 64 + lane) * 4);
  const float scl = 0.08838834764831845f;  // 128^-0.5 folded into q
  size_t qi = ((size_t)head * LQ + l) * HD + 2 * lane;
  bf16x2 qv = {(bf16)((p.x * e0 + p.y * e1) * scl), (bf16)((p.z * e0 + p.w * e1) * scl)};
  bf16x2 kv = {(bf16)(p.x * f0 + p.y * f1), (bf16)(p.z * f0 + p.w * f1)};
  *(bf16x2*)(qh + qi) = qv;
  *(bf16x2*)(kh + qi) = kv;
}

// ---------------- V transpose: y v-part [l][head*HD+d] -> vT [head][d][l] ----------------
__global__ __launch_bounds__(256) void k_vtrans(const bf16* __restrict__ y,
                                                bf16* __restrict__ vT) {
  __shared__ bf16 t[32][34];
  int head = blockIdx.y >> 2, dt = blockIdx.y & 3;
  int tx = threadIdx.x & 31, ty = threadIdx.x >> 5;
  int l0 = blockIdx.x * 32, d0 = dt * 32;
  for (int i = 0; i < 32; i += 8)
    t[ty + i][tx] = y[(size_t)(l0 + ty + i) * (3 * HS) + 2 * HS + head * HD + d0 + tx];
  __syncthreads();
  for (int i = 0; i < 32; i += 8)
    vT[(size_t)(head * HD + d0 + ty + i) * LQ + l0 + tx] = t[tx][ty + i];
}

// ---------------- flash attention: KV-split x4, double-buffered LDS K/V ----------------
// One barrier per tile: barrier -> stage(t+1, buf^1) -> compute(t, buf). The vmcnt(0)
// drain at the NEXT barrier lands after a full tile of compute, hiding load latency.
// K swizzle: 16B slot ^ (row&7) (2-way, free). V swizzle: slot ^ (row&3) (8-way -> 4-way).
__global__ __launch_bounds__(256, 4) void k_attn(
    const bf16* __restrict__ Q, const bf16* __restrict__ Kh,
    const bf16* __restrict__ VT, bf16* __restrict__ Op, float* __restrict__ ml) {
  __shared__ bf16 Ks[2][KVBLK * 128];
  __shared__ bf16 Vs[2][128 * KVBLK];
  __shared__ bf16 P[4][16 * 34];
  int tid = threadIdx.x, lane = tid & 63, w = tid >> 6;
  int b = blockIdx.x;
  int qb = b % 40;
  int split = (b / 40) % SPLIT;
  int head = b / (40 * SPLIT);
  int qr = qb * 64 + w * 16;
  int r16 = lane & 15, g = lane >> 4;
  const bf16* qp = Q + ((size_t)head * LQ + qr + r16) * HD + g * 8;
  bf16x8 qf[4];
#pragma unroll
  for (int c = 0; c < 4; c++) qf[c] = *(const bf16x8*)(qp + c * 32);
  f32x4 O[8] = {};
  float mr[4], lr[4];
#pragma unroll
  for (int i = 0; i < 4; i++) { mr[i] = -1e30f; lr[i] = 0.f; }
  bf16* pl = &P[w][0];
  const bf16* kbase = Kh + ((size_t)head * LQ + split * KVS) * HD;
  const bf16* vbase = VT + (size_t)head * HD * LQ + split * KVS;
  int krow0 = w * 8 + (lane >> 4);
  int kslot = lane & 15;
  int vrow0 = w * 32 + (lane >> 2);
  int vslot = lane & 3;
  auto stage = [&](int buf, int t) {
    int kv0 = t * KVBLK;
#pragma unroll
    for (int i = 0; i < 2; i++) {
      int krow = krow0 + i * 4;
      gl_lds16(kbase + (size_t)(kv0 + krow) * HD + ((kslot ^ (krow & 7)) << 3),
               &Ks[buf][(w * 8 + i * 4) * 128]);
      int vrow = vrow0 + i * 16;
      gl_lds16(vbase + (size_t)vrow * LQ + kv0 + ((vslot ^ (vrow & 3)) << 3),
               &Vs[buf][(w * 32 + i * 16) * KVBLK]);
    }
  };
  stage(0, 0);
  int cur = 0;
  for (int t = 0; t < NTILES; t++) {
    __syncthreads();
    if (t + 1 < NTILES) stage(cur ^ 1, t + 1);
    const bf16* ks = &Ks[cur][0];
    const bf16* vs = &Vs[cur][0];
    f32x4 S0 = {}, S1 = {};
    int sw = (r16 & 7);
#pragma unroll
    for (int c = 0; c < 4; c++) {
      int slot = ((4 * c + g) ^ sw) << 3;
      bf16x8 ka = *(const bf16x8*)&ks[r16 * 128 + slot];
      bf16x8 kb = *(const bf16x8*)&ks[(16 + r16) * 128 + slot];
      S0 = mfma16(qf[c], ka, S0);
      S1 = mfma16(qf[c], kb, S1);
    }
    float alpha[4];
#pragma unroll
    for (int i = 0; i < 4; i++) {
      float mx = fmaxf(S0[i], S1[i]);
#pragma unroll
      for (int m = 8; m; m >>= 1) mx = fmaxf(mx, __shfl_xor(mx, m));
      float mn = fmaxf(mr[i], mx);
      float p0 = __expf(S0[i] - mn), p1 = __expf(S1[i] - mn);
      float rs = p0 + p1;
#pragma unroll
      for (int m = 8; m; m >>= 1) rs += __shfl_xor(rs, m);
      alpha[i] = __expf(mr[i] - mn);
      lr[i] = lr[i] * alpha[i] + rs;
      mr[i] = mn;
      pl[(4 * g + i) * 34 + r16] = (bf16)p0;
      pl[(4 * g + i) * 34 + 16 + r16] = (bf16)p1;
    }
    bf16x8 pf = *(const bf16x8*)&pl[r16 * 34 + g * 8];
    int vsl = (g ^ (r16 & 3)) * 8;
#pragma unroll
    for (int n = 0; n < 8; n++) {
      f32x4 o = O[n];
#pragma unroll
      for (int i = 0; i < 4; i++) o[i] *= alpha[i];
      bf16x8 vf = *(const bf16x8*)&vs[(n * 16 + r16) * KVBLK + vsl];
      O[n] = mfma16(pf, vf, o);
    }
    cur ^= 1;
  }
  const int NL = NH * LQ;
  bf16* op = Op + (size_t)split * NL * HD;
#pragma unroll
  for (int n = 0; n < 8; n++)
#pragma unroll
    for (int i = 0; i < 4; i++)
      op[((size_t)head * LQ + qr + 4 * g + i) * HD + n * 16 + r16] = (bf16)O[n][i];
  if (r16 == 0) {
#pragma unroll
    for (int i = 0; i < 4; i++) {
      int idx = head * LQ + qr + 4 * g + i;
      ml[(size_t)(split * 2 + 0) * NL + idx] = mr[i];
      ml[(size_t)(split * 2 + 1) * NL + idx] = lr[i];
    }
  }
}

// ---------------- combine SPLIT KV-parts -> attnb [l][head*HD+d] bf16 ----------------
__global__ __launch_bounds__(256) void k_attn_combine(
    const bf16* __restrict__ Op, const float* __restrict__ ml, bf16* __restrict__ out) {
  int lane = threadIdx.x & 63, w = threadIdx.x >> 6;
  int row = blockIdx.x * 4 + w;  // head*LQ + l
  int head = row / LQ, l = row - head * LQ;
  const int NL = NH * LQ;
  float ms[SPLIT], ls[SPLIT], m = -1e30f;
#pragma unroll
  for (int s = 0; s < SPLIT; s++) {
    ms[s] = ml[(size_t)(s * 2) * NL + row];
    ls[s] = ml[(size_t)(s * 2 + 1) * NL + row];
    m = fmaxf(m, ms[s]);
  }
  float wsum = 0.f, wgt[SPLIT];
#pragma unroll
  for (int s = 0; s < SPLIT; s++) { wgt[s] = __expf(ms[s] - m); wsum += wgt[s] * ls[s]; }
  float inv = 1.f / wsum;
  size_t oi = (size_t)row * HD + 2 * lane;
  float a0 = 0.f, a1 = 0.f;
#pragma unroll
  for (int s = 0; s < SPLIT; s++) {
    bf16x2 v = *(const bf16x2*)(Op + (size_t)s * NL * HD + oi);
    a0 += wgt[s] * (float)v[0];
    a1 += wgt[s] * (float)v[1];
  }
  bf16x2 ov = {(bf16)(a0 * inv), (bf16)(a1 * inv)};
  *(bf16x2*)(out + (size_t)l * HS + head * HD + 2 * lane) = ov;
}

// ---------------- launch ----------------
extern "C" void kernel_launch(void* const* d_in, const int* in_sizes, int n_in,
                              void* d_out, int out_size, void* d_ws, size_t ws_size,
                              hipStream_t stream) {
  const float* img = (const float*)d_in[0];
  const float* txt = (const float*)d_in[1];
  const float* vec = (const float*)d_in[2];
  const float* pe = (const float*)d_in[3];
#define PARAM(i) ((const float*)d_in[i])

  char* ws = (char*)d_ws;
  size_t off = 0;
  auto alloc = [&](size_t b) { void* p = ws + off; off += (b + 255) & ~(size_t)255; return p; };
  float* silu_s = (float*)alloc((size_t)HS * 4);
  float* mpart = (float*)alloc((size_t)8 * 2 * 12288 * 4);
  float* mod = (float*)alloc((size_t)2 * 6 * HS * 4);
  bf16* qkvT0 = (bf16*)alloc((size_t)3 * HS * HS * 2);
  bf16* qkvT1 = (bf16*)alloc((size_t)3 * HS * HS * 2);
  bf16* projT0 = (bf16*)alloc((size_t)HS * HS * 2);
  bf16* projT1 = (bf16*)alloc((size_t)HS * HS * 2);
  bf16* mlp1T0 = (bf16*)alloc((size_t)MLP_D * HS * 2);
  bf16* mlp1T1 = (bf16*)alloc((size_t)MLP_D * HS * 2);
  bf16* mlp2T0 = (bf16*)alloc((size_t)HS * MLP_D * 2);
  bf16* mlp2T1 = (bf16*)alloc((size_t)HS * MLP_D * 2);
  bf16* xm = (bf16*)alloc((size_t)LQ * HS * 2);
  bf16* y = (bf16*)alloc((size_t)LQ * 3 * HS * 2);
  bf16* qh = (bf16*)alloc((size_t)NH * LQ * HD * 2);
  bf16* kh = (bf16*)alloc((size_t)NH * LQ * HD * 2);
  bf16* vT = (bf16*)alloc((size_t)NH * HD * LQ * 2);
  bf16* attnb = (bf16*)alloc((size_t)LQ * HS * 2);
  float* x2 = (float*)alloc((size_t)LQ * HS * 4);
  bf16* xm2 = (bf16*)alloc((size_t)LQ * HS * 2);
  bf16* h = (bf16*)alloc((size_t)LQ * MLP_D * 2);
  float* ml = (float*)alloc((size_t)2 * SPLIT * NH * LQ * 4);
  // aliases (regions dead at time of use):
  bf16* Op = h;                 // attn partials (4 x 10.5MB) in h, dead until step 9
  float* skpart = (float*)xm;   // split-K partials: proj 2x21MB fits xm+y (42MB);
                                // mlp2 4x21MB fits xm..attnb (exactly 84MB)
  (void)ws_size; (void)in_sizes; (void)n_in; (void)out_size;

  const float* t_mod = mod;
  const float* i_mod = mod + 6 * HS;

  // 1) modulation vectors
  k_silu<<<HS / 256, 256, 0, stream>>>(vec, silu_s);
  k_mod_partial<<<dim3(96, 8), 256, 0, stream>>>(silu_s, PARAM(20), PARAM(4), mpart);
  k_mod_reduce<<<96, 256, 0, stream>>>(mpart, PARAM(21), PARAM(5), mod);

  // 2) weight transpose+cvt (64x64 tiles)
  k_transpose_cvt<<<dim3(3 * HS / 64, HS / 64), 256, 0, stream>>>(PARAM(24), qkvT0, HS, 3 * HS);
  k_transpose_cvt<<<dim3(3 * HS / 64, HS / 64), 256, 0, stream>>>(PARAM(8), qkvT1, HS, 3 * HS);
  k_transpose_cvt<<<dim3(HS / 64, HS / 64), 256, 0, stream>>>(PARAM(28), projT0, HS, HS);
  k_transpose_cvt<<<dim3(HS / 64, HS / 64), 256, 0, stream>>>(PARAM(12), projT1, HS, HS);
  k_transpose_cvt<<<dim3(MLP_D / 64, HS / 64), 256, 0, stream>>>(PARAM(32), mlp1T0, HS, MLP_D);
  k_transpose_cvt<<<dim3(MLP_D / 64, HS / 64), 256, 0, stream>>>(PARAM(16), mlp1T1, HS, MLP_D);
  k_transpose_cvt<<<dim3(HS / 64, MLP_D / 64), 256, 0, stream>>>(PARAM(34), mlp2T0, MLP_D, HS);
  k_transpose_cvt<<<dim3(HS / 64, MLP_D / 64), 256, 0, stream>>>(PARAM(18), mlp2T1, MLP_D, HS);

  // 3) LN1 + modulate
  k_ln_mod<<<LQ, 256, 0, stream>>>(txt, img, PARAM(22), PARAM(23), PARAM(6), PARAM(7),
                                   t_mod, i_mod, 0, 1, xm);

  // 4) qkv GEMM
  k_gemm<0><<<dim3(3 * HS / 128, LQ / 128), 256, 0, stream>>>(
      xm, HS, 3 * HS, HS, qkvT0, qkvT1, PARAM(25), PARAM(9), y, y + (size_t)LT * 3 * HS);

  // 5) RMS + RoPE ; V transpose
  k_qkv_post<<<NH * LQ / 4, 256, 0, stream>>>(y, pe, PARAM(26), PARAM(27), PARAM(10), PARAM(11),
                                              qh, kh);
  k_vtrans<<<dim3(LQ / 32, NH * 4), 256, 0, stream>>>(y, vT);

  // 6) attention (KV-split x4, double-buffered LDS) + combine
  k_attn<<<NH * SPLIT * 40, 256, 0, stream>>>(qh, kh, vT, Op, ml);
  k_attn_combine<<<NH * LQ / 4, 256, 0, stream>>>(Op, ml, attnb);

  // 7) proj GEMM split-K x2 (f32 partials alias xm+y) + combine -> x2
  k_gemm<4><<<dim3(HS / 128, LQ / 128, 2), 256, 0, stream>>>(
      attnb, HS, HS, HS / 2, projT0, projT1, nullptr, nullptr, skpart, nullptr);
  k_skcomb<2><<<LQ * HS / 4 / 256, 256, 0, stream>>>(
      skpart, HS, PARAM(29), PARAM(13), t_mod + 2 * HS, i_mod + 2 * HS, txt, img,
      x2, x2 + (size_t)LT * HS);

  // 8) LN2 + modulate
  k_ln_mod<<<LQ, 256, 0, stream>>>(x2, x2 + (size_t)LT * HS, PARAM(30), PARAM(31), PARAM(14),
                                   PARAM(15), t_mod, i_mod, 3, 4, xm2);

  // 9) MLP1 + gelu
  k_gemm<2><<<dim3(MLP_D / 128, LQ / 128), 256, 0, stream>>>(
      xm2, HS, MLP_D, HS, mlp1T0, mlp1T1, PARAM(33), PARAM(17), h, h + (size_t)LT * MLP_D);

  // 10) MLP2 split-K x4 (f32 partials alias xm..attnb) + combine -> d_out (img first)
  float* out_img = (float*)d_out;
  float* out_txt = (float*)d_out + (size_t)LI * HS;
  k_gemm<4><<<dim3(HS / 128, LQ / 128, 4), 256, 0, stream>>>(
      h, MLP_D, HS, MLP_D / 4, mlp2T0, mlp2T1, nullptr, nullptr, skpart, nullptr);
  k_skcomb<4><<<LQ * HS / 4 / 256, 256, 0, stream>>>(
      skpart, HS, PARAM(35), PARAM(19), t_mod + 5 * HS, i_mod + 5 * HS, x2,
      x2 + (size_t)LT * HS, out_txt, out_img);
}

// Round 6
// 822.750 us; speedup vs baseline: 1.4359x; 1.0458x over previous
//
#include <hip/hip_runtime.h>
#include <hip/hip_bf16.h>
#include <math.h>

typedef __bf16 bf16;
typedef __bf16 bf16x2 __attribute__((ext_vector_type(2)));
typedef __bf16 bf16x8 __attribute__((ext_vector_type(8)));
typedef float f32x4 __attribute__((ext_vector_type(4)));

#define HS 2048
#define NH 16
#define HD 128
#define LT 512
#define LI 2048
#define LQ 2560
#define MLP_D 8192
#define SPLIT 4
#define KVS (LQ / SPLIT)  // 640 kv per split
#define KVBLK 32
#define NTILES (KVS / KVBLK)  // 20

__device__ __forceinline__ f32x4 mfma16(bf16x8 a, bf16x8 b, f32x4 c) {
  return __builtin_amdgcn_mfma_f32_16x16x32_bf16(a, b, c, 0, 0, 0);
}

// async global->LDS, 16B per lane; lds dest must be wave-uniform base (+lane*16 by HW)
__device__ __forceinline__ void gl_lds16(const bf16* g, bf16* l) {
  __builtin_amdgcn_global_load_lds((const __attribute__((address_space(1))) void*)g,
                                   (__attribute__((address_space(3))) void*)l, 16, 0, 0);
}

// ---------------- silu(vec) ----------------
__global__ void k_silu(const float* __restrict__ v, float* __restrict__ s) {
  int i = blockIdx.x * 256 + threadIdx.x;
  float x = v[i];
  s[i] = x / (1.f + expf(-x));
}

// ---------------- mod GEMV: silu(vec) @ mod_w, 2-pass (deterministic) ----------------
__global__ __launch_bounds__(256) void k_mod_partial(
    const float* __restrict__ s, const float* __restrict__ w_txt,
    const float* __restrict__ w_img, float* __restrict__ part) {
  int strm = blockIdx.x / 48;
  int n = (blockIdx.x % 48) * 256 + threadIdx.x;
  const float* w = strm ? w_img : w_txt;
  int k0 = blockIdx.y * 256;
  __shared__ float sl[256];
  sl[threadIdx.x] = s[k0 + threadIdx.x];
  __syncthreads();
  float acc = 0.f;
  for (int k = 0; k < 256; k++)
    acc += sl[k] * w[(size_t)(k0 + k) * 12288 + n];
  part[((size_t)blockIdx.y * 2 + strm) * 12288 + n] = acc;
}

__global__ __launch_bounds__(256) void k_mod_reduce(
    const float* __restrict__ part, const float* __restrict__ b_txt,
    const float* __restrict__ b_img, float* __restrict__ mod) {
  int strm = blockIdx.x / 48;
  int n = (blockIdx.x % 48) * 256 + threadIdx.x;
  float acc = strm ? b_img[n] : b_txt[n];
  for (int kc = 0; kc < 8; kc++)
    acc += part[((size_t)kc * 2 + strm) * 12288 + n];
  mod[(size_t)strm * 12288 + n] = acc;
}

// ---------------- weight transpose + fp32->bf16 : src[R][C] -> dst[C][R] ----------------
// 64x64 tile; reads coalesced f32 rows, writes coalesced bf16x8 (16B/lane) rows of dst.
__global__ __launch_bounds__(256) void k_transpose_cvt(
    const float* __restrict__ src, bf16* __restrict__ dst, int R, int C) {
  __shared__ float t[64][65];
  int tx = threadIdx.x & 63, ty = threadIdx.x >> 6;
  int c0 = blockIdx.x * 64, r0 = blockIdx.y * 64;
  for (int i = 0; i < 64; i += 4)
    t[ty + i][tx] = src[(size_t)(r0 + ty + i) * C + c0 + tx];
  __syncthreads();
#pragma unroll
  for (int j = 0; j < 2; j++) {
    int c = (threadIdx.x >> 3) + j * 32;
    int gg = (threadIdx.x & 7) * 8;
    bf16x8 ov;
#pragma unroll
    for (int k = 0; k < 8; k++) ov[k] = (bf16)t[gg + k][c];
    *(bf16x8*)(dst + (size_t)(c0 + c) * R + r0 + gg) = ov;
  }
}

// ---------------- LayerNorm + modulate -> bf16 ----------------
__global__ __launch_bounds__(256) void k_ln_mod(
    const float* __restrict__ x0, const float* __restrict__ x1,
    const float* __restrict__ ls0, const float* __restrict__ lb0,
    const float* __restrict__ ls1, const float* __restrict__ lb1,
    const float* __restrict__ mod0, const float* __restrict__ mod1,
    int shidx, int scidx, bf16* __restrict__ out) {
  int r = blockIdx.x;
  int strm = r >= LT;
  const float* x = strm ? (x1 + (size_t)(r - LT) * HS) : (x0 + (size_t)r * HS);
  const float* ls = strm ? ls1 : ls0;
  const float* lb = strm ? lb1 : lb0;
  const float* md = strm ? mod1 : mod0;
  const float* sh = md + (size_t)shidx * HS;
  const float* sc = md + (size_t)scidx * HS;
  int t = threadIdx.x;
  float4 a = ((const float4*)x)[t * 2];
  float4 b = ((const float4*)x)[t * 2 + 1];
  float xv[8] = {a.x, a.y, a.z, a.w, b.x, b.y, b.z, b.w};
  float sum = 0.f, sq = 0.f;
#pragma unroll
  for (int j = 0; j < 8; j++) { sum += xv[j]; sq += xv[j] * xv[j]; }
#pragma unroll
  for (int m = 32; m; m >>= 1) { sum += __shfl_xor(sum, m); sq += __shfl_xor(sq, m); }
  __shared__ float red[8];
  int lane = t & 63, wid = t >> 6;
  if (!lane) { red[wid] = sum; red[wid + 4] = sq; }
  __syncthreads();
  float ts = red[0] + red[1] + red[2] + red[3];
  float tq = red[4] + red[5] + red[6] + red[7];
  float mean = ts * (1.f / HS);
  float var = tq * (1.f / HS) - mean * mean;
  float inv = rsqrtf(var + 1e-6f);
  int c0 = t * 8;
  bf16x8 ov;
#pragma unroll
  for (int j = 0; j < 8; j++) {
    int c = c0 + j;
    float v = ((xv[j] - mean) * inv * ls[c] + lb[c]) * (1.f + sc[c]) + sh[c];
    ov[j] = (bf16)v;
  }
  *(bf16x8*)(out + (size_t)r * HS + c0) = ov;
}

// ---------------- GEMM: A[2560][K] bf16 @ BT[N][K] bf16, dual-stream weights ----------------
// Double-buffered LDS, ONE barrier per K-step: barrier -> stage(next,buf^1) -> frags+MFMA(buf).
// The vmcnt(0) drain at the NEXT barrier lands after a full K-step of compute.
// LDS both-sides XOR swizzle: 16B slot ^ (row&3) (8-way -> 4-way frag-read conflict).
// MODE 0: out bf16 = acc+bias (qkv) ; 2: bf16 gelu(acc+bias) (mlp1)
// MODE 4: f32 partial (split-K over blockIdx.z, Ksz cols each), no bias
template <int MODE>
__global__ __launch_bounds__(256) void k_gemm(
    const bf16* __restrict__ A, int K, int N, int Ksz,
    const bf16* __restrict__ BT0, const bf16* __restrict__ BT1,
    const float* __restrict__ bias0, const float* __restrict__ bias1,
    void* __restrict__ out0, void* __restrict__ out1) {
  __shared__ bf16 As[2][128 * 32];
  __shared__ bf16 Bs[2][128 * 32];
  int tid = threadIdx.x;
  int bn = blockIdx.x, bm = blockIdx.y;
  int strm = (bm * 128) >= LT;
  int lm = bm * 128 - strm * LT;
  const bf16* BT = strm ? BT1 : BT0;
  int lane = tid & 63, wid = tid >> 6;
  int wr = wid >> 1, wc = wid & 1;
  int sr = tid >> 2;                       // staged row (0..63 within half)
  int scol = ((tid & 3) ^ (sr & 3)) * 8;   // pre-swizzled global col slot
  const bf16* Ag = A + (size_t)(bm * 128 + sr) * K + scol;
  const bf16* Bg = BT + (size_t)(bn * 128 + sr) * K + scol;
  int kbeg = MODE == 4 ? blockIdx.z * Ksz : 0;
  int nk = Ksz / 32;
  auto stage = [&](int buf, int ks) {
    int k0 = kbeg + ks * 32;
    gl_lds16(Ag + k0, &As[buf][wid * 512]);
    gl_lds16(Ag + (size_t)64 * K + k0, &As[buf][2048 + wid * 512]);
    gl_lds16(Bg + k0, &Bs[buf][wid * 512]);
    gl_lds16(Bg + (size_t)64 * K + k0, &Bs[buf][2048 + wid * 512]);
  };
  f32x4 acc[4][4] = {};
  int r16 = lane & 15, g = lane >> 4;
  int fslot = (g ^ (r16 & 3)) * 8;  // swizzled frag slot (row&3 == r16&3 for all frag rows)
  stage(0, 0);
  int cur = 0;
  for (int ks = 0; ks < nk; ks++) {
    __syncthreads();
    if (ks + 1 < nk) stage(cur ^ 1, ks + 1);
    bf16x8 af[4], bfr[4];
#pragma unroll
    for (int m = 0; m < 4; m++)
      af[m] = *(const bf16x8*)&As[cur][(wr * 64 + m * 16 + r16) * 32 + fslot];
#pragma unroll
    for (int n = 0; n < 4; n++)
      bfr[n] = *(const bf16x8*)&Bs[cur][(wc * 64 + n * 16 + r16) * 32 + fslot];
#pragma unroll
    for (int m = 0; m < 4; m++)
#pragma unroll
      for (int n = 0; n < 4; n++)
        acc[m][n] = mfma16(af[m], bfr[n], acc[m][n]);
    cur ^= 1;
  }
  int col = lane & 15, rb = (lane >> 4) * 4;
  const float* bias = strm ? bias1 : bias0;
  float* part = MODE == 4 ? (float*)out0 + (size_t)blockIdx.z * LQ * N : nullptr;
#pragma unroll
  for (int m = 0; m < 4; m++) {
#pragma unroll
    for (int n = 0; n < 4; n++) {
      int gn = bn * 128 + wc * 64 + n * 16 + col;
      float bv = MODE == 4 ? 0.f : bias[gn];
#pragma unroll
      for (int r = 0; r < 4; r++) {
        int lr = wr * 64 + m * 16 + rb + r;
        float v = acc[m][n][r] + bv;
        if (MODE == 0) {
          ((bf16*)(strm ? out1 : out0))[(size_t)(lm + lr) * N + gn] = (bf16)v;
        } else if (MODE == 2) {
          // gelu_tanh == v * sigmoid(2u), u = 0.79788456*(v + 0.044715 v^3)  (exact identity)
          float u2 = 1.5957691216057308f * (v + 0.044715f * v * v * v);
          float ge = v / (1.f + __expf(-u2));
          ((bf16*)(strm ? out1 : out0))[(size_t)(lm + lr) * N + gn] = (bf16)ge;
        } else {
          part[(size_t)(bm * 128 + lr) * N + gn] = v;
        }
      }
    }
  }
}

// ---------------- split-K combine: out = res + gate*(sum(part)+bias), f32 ----------------
template <int S>
__global__ __launch_bounds__(256) void k_skcomb(
    const float* __restrict__ part, int N,
    const float* __restrict__ bias0, const float* __restrict__ bias1,
    const float* __restrict__ gate0, const float* __restrict__ gate1,
    const float* __restrict__ res0, const float* __restrict__ res1,
    float* __restrict__ out0, float* __restrict__ out1) {
  int gid = blockIdx.x * 256 + threadIdx.x;
  int nv = N >> 2;
  int row = gid / nv, cv = gid - row * nv;
  int strm = row >= LT;
  int lrow = row - strm * LT;
  const float* bias = strm ? bias1 : bias0;
  const float* gate = strm ? gate1 : gate0;
  const float* res = strm ? res1 : res0;
  float* out = strm ? out1 : out0;
  int c = cv * 4;
  float4 acc = *(const float4*)(bias + c);
#pragma unroll
  for (int s = 0; s < S; s++) {
    float4 p = *(const float4*)(part + ((size_t)s * LQ + row) * N + c);
    acc.x += p.x; acc.y += p.y; acc.z += p.z; acc.w += p.w;
  }
  float4 g = *(const float4*)(gate + c);
  float4 r = *(const float4*)(res + (size_t)lrow * N + c);
  float4 o = {r.x + g.x * acc.x, r.y + g.y * acc.y, r.z + g.z * acc.z, r.w + g.w * acc.w};
  *(float4*)(out + (size_t)lrow * N + c) = o;
}

// ---------------- qkv post: RMS norm (q,k) + RoPE + scale ----------------
__global__ __launch_bounds__(256) void k_qkv_post(
    const bf16* __restrict__ y, const float* __restrict__ pe,
    const float* __restrict__ qn0, const float* __restrict__ kn0,
    const float* __restrict__ qn1, const float* __restrict__ kn1,
    bf16* __restrict__ qh, bf16* __restrict__ kh) {
  int wv = (int)((blockIdx.x * 256 + threadIdx.x) >> 6);
  int lane = threadIdx.x & 63;
  int head = wv / LQ, l = wv - head * LQ;
  const bf16* yr = y + (size_t)l * (3 * HS) + head * HD;
  float q0 = (float)yr[2 * lane], q1 = (float)yr[2 * lane + 1];
  float k0 = (float)yr[HS + 2 * lane], k1 = (float)yr[HS + 2 * lane + 1];
  float sqs = q0 * q0 + q1 * q1, sks = k0 * k0 + k1 * k1;
#pragma unroll
  for (int m = 1; m < 64; m <<= 1) { sqs += __shfl_xor(sqs, m); sks += __shfl_xor(sks, m); }
  float rq = rsqrtf(sqs * (1.f / HD) + 1e-6f);
  float rk = rsqrtf(sks * (1.f / HD) + 1e-6f);
  int strm = l >= LT;
  const float* qn = strm ? qn1 : qn0;
  const float* kn = strm ? kn1 : kn0;
  float e0 = q0 * rq * qn[2 * lane], e1 = q1 * rq * qn[2 * lane + 1];
  float f0 = k0 * rk * kn[2 * lane], f1 = k1 * rk * kn[2 * lane + 1];
  float4 p = *(const float4*)(pe + ((size_t)l * 64 + lane) * 4);
  const float scl = 0.08838834764831845f;  // 128^-0.5 folded into q
  size_t qi = ((size_t)head * LQ + l) * HD + 2 * lane;
  bf16x2 qv = {(bf16)((p.x * e0 + p.y * e1) * scl), (bf16)((p.z * e0 + p.w * e1) * scl)};
  bf16x2 kv = {(bf16)(p.x * f0 + p.y * f1), (bf16)(p.z * f0 + p.w * f1)};
  *(bf16x2*)(qh + qi) = qv;
  *(bf16x2*)(kh + qi) = kv;
}

// ---------------- V transpose: y v-part [l][head*HD+d] -> vT [head][d][l] ----------------
__global__ __launch_bounds__(256) void k_vtrans(const bf16* __restrict__ y,
                                                bf16* __restrict__ vT) {
  __shared__ bf16 t[32][34];
  int head = blockIdx.y >> 2, dt = blockIdx.y & 3;
  int tx = threadIdx.x & 31, ty = threadIdx.x >> 5;
  int l0 = blockIdx.x * 32, d0 = dt * 32;
  for (int i = 0; i < 32; i += 8)
    t[ty + i][tx] = y[(size_t)(l0 + ty + i) * (3 * HS) + 2 * HS + head * HD + d0 + tx];
  __syncthreads();
  for (int i = 0; i < 32; i += 8)
    vT[(size_t)(head * HD + d0 + ty + i) * LQ + l0 + tx] = t[tx][ty + i];
}

// ---------------- flash attention: KV-split x4, double-buffered LDS K/V ----------------
__global__ __launch_bounds__(256, 4) void k_attn(
    const bf16* __restrict__ Q, const bf16* __restrict__ Kh,
    const bf16* __restrict__ VT, bf16* __restrict__ Op, float* __restrict__ ml) {
  __shared__ bf16 Ks[2][KVBLK * 128];
  __shared__ bf16 Vs[2][128 * KVBLK];
  __shared__ bf16 P[4][16 * 34];
  int tid = threadIdx.x, lane = tid & 63, w = tid >> 6;
  int b = blockIdx.x;
  int qb = b % 40;
  int split = (b / 40) % SPLIT;
  int head = b / (40 * SPLIT);
  int qr = qb * 64 + w * 16;
  int r16 = lane & 15, g = lane >> 4;
  const bf16* qp = Q + ((size_t)head * LQ + qr + r16) * HD + g * 8;
  bf16x8 qf[4];
#pragma unroll
  for (int c = 0; c < 4; c++) qf[c] = *(const bf16x8*)(qp + c * 32);
  f32x4 O[8] = {};
  float mr[4], lr[4];
#pragma unroll
  for (int i = 0; i < 4; i++) { mr[i] = -1e30f; lr[i] = 0.f; }
  bf16* pl = &P[w][0];
  const bf16* kbase = Kh + ((size_t)head * LQ + split * KVS) * HD;
  const bf16* vbase = VT + (size_t)head * HD * LQ + split * KVS;
  int krow0 = w * 8 + (lane >> 4);
  int kslot = lane & 15;
  int vrow0 = w * 32 + (lane >> 2);
  int vslot = lane & 3;
  auto stage = [&](int buf, int t) {
    int kv0 = t * KVBLK;
#pragma unroll
    for (int i = 0; i < 2; i++) {
      int krow = krow0 + i * 4;
      gl_lds16(kbase + (size_t)(kv0 + krow) * HD + ((kslot ^ (krow & 7)) << 3),
               &Ks[buf][(w * 8 + i * 4) * 128]);
      int vrow = vrow0 + i * 16;
      gl_lds16(vbase + (size_t)vrow * LQ + kv0 + ((vslot ^ (vrow & 3)) << 3),
               &Vs[buf][(w * 32 + i * 16) * KVBLK]);
    }
  };
  stage(0, 0);
  int cur = 0;
  for (int t = 0; t < NTILES; t++) {
    __syncthreads();
    if (t + 1 < NTILES) stage(cur ^ 1, t + 1);
    const bf16* ks = &Ks[cur][0];
    const bf16* vs = &Vs[cur][0];
    f32x4 S0 = {}, S1 = {};
    int sw = (r16 & 7);
#pragma unroll
    for (int c = 0; c < 4; c++) {
      int slot = ((4 * c + g) ^ sw) << 3;
      bf16x8 ka = *(const bf16x8*)&ks[r16 * 128 + slot];
      bf16x8 kb = *(const bf16x8*)&ks[(16 + r16) * 128 + slot];
      S0 = mfma16(qf[c], ka, S0);
      S1 = mfma16(qf[c], kb, S1);
    }
    float alpha[4];
#pragma unroll
    for (int i = 0; i < 4; i++) {
      float mx = fmaxf(S0[i], S1[i]);
#pragma unroll
      for (int m = 8; m; m >>= 1) mx = fmaxf(mx, __shfl_xor(mx, m));
      float mn = fmaxf(mr[i], mx);
      float p0 = __expf(S0[i] - mn), p1 = __expf(S1[i] - mn);
      float rs = p0 + p1;
#pragma unroll
      for (int m = 8; m; m >>= 1) rs += __shfl_xor(rs, m);
      alpha[i] = __expf(mr[i] - mn);
      lr[i] = lr[i] * alpha[i] + rs;
      mr[i] = mn;
      pl[(4 * g + i) * 34 + r16] = (bf16)p0;
      pl[(4 * g + i) * 34 + 16 + r16] = (bf16)p1;
    }
    bf16x8 pf = *(const bf16x8*)&pl[r16 * 34 + g * 8];
    int vsl = (g ^ (r16 & 3)) * 8;
#pragma unroll
    for (int n = 0; n < 8; n++) {
      f32x4 o = O[n];
#pragma unroll
      for (int i = 0; i < 4; i++) o[i] *= alpha[i];
      bf16x8 vf = *(const bf16x8*)&vs[(n * 16 + r16) * KVBLK + vsl];
      O[n] = mfma16(pf, vf, o);
    }
    cur ^= 1;
  }
  const int NL = NH * LQ;
  bf16* op = Op + (size_t)split * NL * HD;
#pragma unroll
  for (int n = 0; n < 8; n++)
#pragma unroll
    for (int i = 0; i < 4; i++)
      op[((size_t)head * LQ + qr + 4 * g + i) * HD + n * 16 + r16] = (bf16)O[n][i];
  if (r16 == 0) {
#pragma unroll
    for (int i = 0; i < 4; i++) {
      int idx = head * LQ + qr + 4 * g + i;
      ml[(size_t)(split * 2 + 0) * NL + idx] = mr[i];
      ml[(size_t)(split * 2 + 1) * NL + idx] = lr[i];
    }
  }
}

// ---------------- combine SPLIT KV-parts -> attnb [l][head*HD+d] bf16 ----------------
__global__ __launch_bounds__(256) void k_attn_combine(
    const bf16* __restrict__ Op, const float* __restrict__ ml, bf16* __restrict__ out) {
  int lane = threadIdx.x & 63, w = threadIdx.x >> 6;
  int row = blockIdx.x * 4 + w;  // head*LQ + l
  int head = row / LQ, l = row - head * LQ;
  const int NL = NH * LQ;
  float ms[SPLIT], ls[SPLIT], m = -1e30f;
#pragma unroll
  for (int s = 0; s < SPLIT; s++) {
    ms[s] = ml[(size_t)(s * 2) * NL + row];
    ls[s] = ml[(size_t)(s * 2 + 1) * NL + row];
    m = fmaxf(m, ms[s]);
  }
  float wsum = 0.f, wgt[SPLIT];
#pragma unroll
  for (int s = 0; s < SPLIT; s++) { wgt[s] = __expf(ms[s] - m); wsum += wgt[s] * ls[s]; }
  float inv = 1.f / wsum;
  size_t oi = (size_t)row * HD + 2 * lane;
  float a0 = 0.f, a1 = 0.f;
#pragma unroll
  for (int s = 0; s < SPLIT; s++) {
    bf16x2 v = *(const bf16x2*)(Op + (size_t)s * NL * HD + oi);
    a0 += wgt[s] * (float)v[0];
    a1 += wgt[s] * (float)v[1];
  }
  bf16x2 ov = {(bf16)(a0 * inv), (bf16)(a1 * inv)};
  *(bf16x2*)(out + (size_t)l * HS + head * HD + 2 * lane) = ov;
}

// ---------------- launch ----------------
extern "C" void kernel_launch(void* const* d_in, const int* in_sizes, int n_in,
                              void* d_out, int out_size, void* d_ws, size_t ws_size,
                              hipStream_t stream) {
  const float* img = (const float*)d_in[0];
  const float* txt = (const float*)d_in[1];
  const float* vec = (const float*)d_in[2];
  const float* pe = (const float*)d_in[3];
#define PARAM(i) ((const float*)d_in[i])

  char* ws = (char*)d_ws;
  size_t off = 0;
  auto alloc = [&](size_t b) { void* p = ws + off; off += (b + 255) & ~(size_t)255; return p; };
  float* silu_s = (float*)alloc((size_t)HS * 4);
  float* mpart = (float*)alloc((size_t)8 * 2 * 12288 * 4);
  float* mod = (float*)alloc((size_t)2 * 6 * HS * 4);
  bf16* qkvT0 = (bf16*)alloc((size_t)3 * HS * HS * 2);
  bf16* qkvT1 = (bf16*)alloc((size_t)3 * HS * HS * 2);
  bf16* projT0 = (bf16*)alloc((size_t)HS * HS * 2);
  bf16* projT1 = (bf16*)alloc((size_t)HS * HS * 2);
  bf16* mlp1T0 = (bf16*)alloc((size_t)MLP_D * HS * 2);
  bf16* mlp1T1 = (bf16*)alloc((size_t)MLP_D * HS * 2);
  bf16* mlp2T0 = (bf16*)alloc((size_t)HS * MLP_D * 2);
  bf16* mlp2T1 = (bf16*)alloc((size_t)HS * MLP_D * 2);
  bf16* xm = (bf16*)alloc((size_t)LQ * HS * 2);
  bf16* y = (bf16*)alloc((size_t)LQ * 3 * HS * 2);
  bf16* qh = (bf16*)alloc((size_t)NH * LQ * HD * 2);
  bf16* kh = (bf16*)alloc((size_t)NH * LQ * HD * 2);
  bf16* vT = (bf16*)alloc((size_t)NH * HD * LQ * 2);
  bf16* attnb = (bf16*)alloc((size_t)LQ * HS * 2);
  float* x2 = (float*)alloc((size_t)LQ * HS * 4);
  bf16* xm2 = (bf16*)alloc((size_t)LQ * HS * 2);
  bf16* h = (bf16*)alloc((size_t)LQ * MLP_D * 2);
  float* ml = (float*)alloc((size_t)2 * SPLIT * NH * LQ * 4);
  // aliases (regions dead at time of use):
  bf16* Op = h;                 // attn partials (4 x 10.5MB) in h, dead until step 9
  float* skpart = (float*)xm;   // split-K partials: proj 2x21MB fits xm+y (42MB);
                                // mlp2 4x21MB fits xm..attnb (exactly 84MB)
  (void)ws_size; (void)in_sizes; (void)n_in; (void)out_size;

  const float* t_mod = mod;
  const float* i_mod = mod + 6 * HS;

  // 1) modulation vectors
  k_silu<<<HS / 256, 256, 0, stream>>>(vec, silu_s);
  k_mod_partial<<<dim3(96, 8), 256, 0, stream>>>(silu_s, PARAM(20), PARAM(4), mpart);
  k_mod_reduce<<<96, 256, 0, stream>>>(mpart, PARAM(21), PARAM(5), mod);

  // 2) weight transpose+cvt (64x64 tiles)
  k_transpose_cvt<<<dim3(3 * HS / 64, HS / 64), 256, 0, stream>>>(PARAM(24), qkvT0, HS, 3 * HS);
  k_transpose_cvt<<<dim3(3 * HS / 64, HS / 64), 256, 0, stream>>>(PARAM(8), qkvT1, HS, 3 * HS);
  k_transpose_cvt<<<dim3(HS / 64, HS / 64), 256, 0, stream>>>(PARAM(28), projT0, HS, HS);
  k_transpose_cvt<<<dim3(HS / 64, HS / 64), 256, 0, stream>>>(PARAM(12), projT1, HS, HS);
  k_transpose_cvt<<<dim3(MLP_D / 64, HS / 64), 256, 0, stream>>>(PARAM(32), mlp1T0, HS, MLP_D);
  k_transpose_cvt<<<dim3(MLP_D / 64, HS / 64), 256, 0, stream>>>(PARAM(16), mlp1T1, HS, MLP_D);
  k_transpose_cvt<<<dim3(HS / 64, MLP_D / 64), 256, 0, stream>>>(PARAM(34), mlp2T0, MLP_D, HS);
  k_transpose_cvt<<<dim3(HS / 64, MLP_D / 64), 256, 0, stream>>>(PARAM(18), mlp2T1, MLP_D, HS);

  // 3) LN1 + modulate
  k_ln_mod<<<LQ, 256, 0, stream>>>(txt, img, PARAM(22), PARAM(23), PARAM(6), PARAM(7),
                                   t_mod, i_mod, 0, 1, xm);

  // 4) qkv GEMM
  k_gemm<0><<<dim3(3 * HS / 128, LQ / 128), 256, 0, stream>>>(
      xm, HS, 3 * HS, HS, qkvT0, qkvT1, PARAM(25), PARAM(9), y, y + (size_t)LT * 3 * HS);

  // 5) RMS + RoPE ; V transpose
  k_qkv_post<<<NH * LQ / 4, 256, 0, stream>>>(y, pe, PARAM(26), PARAM(27), PARAM(10), PARAM(11),
                                              qh, kh);
  k_vtrans<<<dim3(LQ / 32, NH * 4), 256, 0, stream>>>(y, vT);

  // 6) attention (KV-split x4, double-buffered LDS) + combine
  k_attn<<<NH * SPLIT * 40, 256, 0, stream>>>(qh, kh, vT, Op, ml);
  k_attn_combine<<<NH * LQ / 4, 256, 0, stream>>>(Op, ml, attnb);

  // 7) proj GEMM split-K x2 (f32 partials alias xm+y) + combine -> x2
  k_gemm<4><<<dim3(HS / 128, LQ / 128, 2), 256, 0, stream>>>(
      attnb, HS, HS, HS / 2, projT0, projT1, nullptr, nullptr, skpart, nullptr);
  k_skcomb<2><<<LQ * HS / 4 / 256, 256, 0, stream>>>(
      skpart, HS, PARAM(29), PARAM(13), t_mod + 2 * HS, i_mod + 2 * HS, txt, img,
      x2, x2 + (size_t)LT * HS);

  // 8) LN2 + modulate
  k_ln_mod<<<LQ, 256, 0, stream>>>(x2, x2 + (size_t)LT * HS, PARAM(30), PARAM(31), PARAM(14),
                                   PARAM(15), t_mod, i_mod, 3, 4, xm2);

  // 9) MLP1 + gelu
  k_gemm<2><<<dim3(MLP_D / 128, LQ / 128), 256, 0, stream>>>(
      xm2, HS, MLP_D, HS, mlp1T0, mlp1T1, PARAM(33), PARAM(17), h, h + (size_t)LT * MLP_D);

  // 10) MLP2 split-K x4 (f32 partials alias xm..attnb) + combine -> d_out (img first)
  float* out_img = (float*)d_out;
  float* out_txt = (float*)d_out + (size_t)LI * HS;
  k_gemm<4><<<dim3(HS / 128, LQ / 128, 4), 256, 0, stream>>>(
      h, MLP_D, HS, MLP_D / 4, mlp2T0, mlp2T1, nullptr, nullptr, skpart, nullptr);
  k_skcomb<4><<<LQ * HS / 4 / 256, 256, 0, stream>>>(
      skpart, HS, PARAM(35), PARAM(19), t_mod + 5 * HS, i_mod + 5 * HS, x2,
      x2 + (size_t)LT * HS, out_txt, out_img);
}

// Round 7
// 763.084 us; speedup vs baseline: 1.5482x; 1.0782x over previous
//
#include <hip/hip_runtime.h>
#include <hip/hip_bf16.h>
#include <math.h>

typedef __bf16 bf16;
typedef __bf16 bf16x2 __attribute__((ext_vector_type(2)));
typedef __bf16 bf16x4 __attribute__((ext_vector_type(4)));
typedef __bf16 bf16x8 __attribute__((ext_vector_type(8)));
typedef float f32x4 __attribute__((ext_vector_type(4)));

#define HS 2048
#define NH 16
#define HD 128
#define LT 512
#define LI 2048
#define LQ 2560
#define MLP_D 8192
#define SPLIT 4
#define KVS (LQ / SPLIT)  // 640 kv per split
#define KVBLK 32
#define NTILES (KVS / KVBLK)  // 20

__device__ __forceinline__ f32x4 mfma16(bf16x8 a, bf16x8 b, f32x4 c) {
  return __builtin_amdgcn_mfma_f32_16x16x32_bf16(a, b, c, 0, 0, 0);
}

// async global->LDS, 16B per lane; lds dest must be wave-uniform base (+lane*16 by HW)
__device__ __forceinline__ void gl_lds16(const bf16* g, bf16* l) {
  __builtin_amdgcn_global_load_lds((const __attribute__((address_space(1))) void*)g,
                                   (__attribute__((address_space(3))) void*)l, 16, 0, 0);
}

// ---------------- silu(vec) ----------------
__global__ void k_silu(const float* __restrict__ v, float* __restrict__ s) {
  int i = blockIdx.x * 256 + threadIdx.x;
  float x = v[i];
  s[i] = x / (1.f + expf(-x));
}

// ---------------- mod GEMV: silu(vec) @ mod_w, 2-pass (deterministic) ----------------
__global__ __launch_bounds__(256) void k_mod_partial(
    const float* __restrict__ s, const float* __restrict__ w_txt,
    const float* __restrict__ w_img, float* __restrict__ part) {
  int strm = blockIdx.x / 48;
  int n = (blockIdx.x % 48) * 256 + threadIdx.x;
  const float* w = strm ? w_img : w_txt;
  int k0 = blockIdx.y * 256;
  __shared__ float sl[256];
  sl[threadIdx.x] = s[k0 + threadIdx.x];
  __syncthreads();
  float acc = 0.f;
  for (int k = 0; k < 256; k++)
    acc += sl[k] * w[(size_t)(k0 + k) * 12288 + n];
  part[((size_t)blockIdx.y * 2 + strm) * 12288 + n] = acc;
}

__global__ __launch_bounds__(256) void k_mod_reduce(
    const float* __restrict__ part, const float* __restrict__ b_txt,
    const float* __restrict__ b_img, float* __restrict__ mod) {
  int strm = blockIdx.x / 48;
  int n = (blockIdx.x % 48) * 256 + threadIdx.x;
  float acc = strm ? b_img[n] : b_txt[n];
  for (int kc = 0; kc < 8; kc++)
    acc += part[((size_t)kc * 2 + strm) * 12288 + n];
  mod[(size_t)strm * 12288 + n] = acc;
}

// ---------------- weight transpose + fp32->bf16 : src[R][C] -> dst[C][R] ----------------
__global__ __launch_bounds__(256) void k_transpose_cvt(
    const float* __restrict__ src, bf16* __restrict__ dst, int R, int C) {
  __shared__ float t[64][65];
  int tx = threadIdx.x & 63, ty = threadIdx.x >> 6;
  int c0 = blockIdx.x * 64, r0 = blockIdx.y * 64;
  for (int i = 0; i < 64; i += 4)
    t[ty + i][tx] = src[(size_t)(r0 + ty + i) * C + c0 + tx];
  __syncthreads();
#pragma unroll
  for (int j = 0; j < 2; j++) {
    int c = (threadIdx.x >> 3) + j * 32;
    int gg = (threadIdx.x & 7) * 8;
    bf16x8 ov;
#pragma unroll
    for (int k = 0; k < 8; k++) ov[k] = (bf16)t[gg + k][c];
    *(bf16x8*)(dst + (size_t)(c0 + c) * R + r0 + gg) = ov;
  }
}

// ---------------- LayerNorm + modulate -> bf16 ----------------
__global__ __launch_bounds__(256) void k_ln_mod(
    const float* __restrict__ x0, const float* __restrict__ x1,
    const float* __restrict__ ls0, const float* __restrict__ lb0,
    const float* __restrict__ ls1, const float* __restrict__ lb1,
    const float* __restrict__ mod0, const float* __restrict__ mod1,
    int shidx, int scidx, bf16* __restrict__ out) {
  int r = blockIdx.x;
  int strm = r >= LT;
  const float* x = strm ? (x1 + (size_t)(r - LT) * HS) : (x0 + (size_t)r * HS);
  const float* ls = strm ? ls1 : ls0;
  const float* lb = strm ? lb1 : lb0;
  const float* md = strm ? mod1 : mod0;
  const float* sh = md + (size_t)shidx * HS;
  const float* sc = md + (size_t)scidx * HS;
  int t = threadIdx.x;
  float4 a = ((const float4*)x)[t * 2];
  float4 b = ((const float4*)x)[t * 2 + 1];
  float xv[8] = {a.x, a.y, a.z, a.w, b.x, b.y, b.z, b.w};
  float sum = 0.f, sq = 0.f;
#pragma unroll
  for (int j = 0; j < 8; j++) { sum += xv[j]; sq += xv[j] * xv[j]; }
#pragma unroll
  for (int m = 32; m; m >>= 1) { sum += __shfl_xor(sum, m); sq += __shfl_xor(sq, m); }
  __shared__ float red[8];
  int lane = t & 63, wid = t >> 6;
  if (!lane) { red[wid] = sum; red[wid + 4] = sq; }
  __syncthreads();
  float ts = red[0] + red[1] + red[2] + red[3];
  float tq = red[4] + red[5] + red[6] + red[7];
  float mean = ts * (1.f / HS);
  float var = tq * (1.f / HS) - mean * mean;
  float inv = rsqrtf(var + 1e-6f);
  int c0 = t * 8;
  bf16x8 ov;
#pragma unroll
  for (int j = 0; j < 8; j++) {
    int c = c0 + j;
    float v = ((xv[j] - mean) * inv * ls[c] + lb[c]) * (1.f + sc[c]) + sh[c];
    ov[j] = (bf16)v;
  }
  *(bf16x8*)(out + (size_t)r * HS + c0) = ov;
}

// ---------------- GEMM: A[2560][K] bf16 @ BT[N][K] bf16, dual-stream weights ----------------
// Double-buffered LDS, ONE barrier per K-step. Both-sides XOR swizzle (slot^(row&3)).
template <int MODE>
__global__ __launch_bounds__(256) void k_gemm(
    const bf16* __restrict__ A, int K, int N, int Ksz,
    const bf16* __restrict__ BT0, const bf16* __restrict__ BT1,
    const float* __restrict__ bias0, const float* __restrict__ bias1,
    void* __restrict__ out0, void* __restrict__ out1) {
  __shared__ bf16 As[2][128 * 32];
  __shared__ bf16 Bs[2][128 * 32];
  int tid = threadIdx.x;
  int bn = blockIdx.x, bm = blockIdx.y;
  int strm = (bm * 128) >= LT;
  int lm = bm * 128 - strm * LT;
  const bf16* BT = strm ? BT1 : BT0;
  int lane = tid & 63, wid = tid >> 6;
  int wr = wid >> 1, wc = wid & 1;
  int sr = tid >> 2;
  int scol = ((tid & 3) ^ (sr & 3)) * 8;
  const bf16* Ag = A + (size_t)(bm * 128 + sr) * K + scol;
  const bf16* Bg = BT + (size_t)(bn * 128 + sr) * K + scol;
  int kbeg = MODE == 4 ? blockIdx.z * Ksz : 0;
  int nk = Ksz / 32;
  auto stage = [&](int buf, int ks) {
    int k0 = kbeg + ks * 32;
    gl_lds16(Ag + k0, &As[buf][wid * 512]);
    gl_lds16(Ag + (size_t)64 * K + k0, &As[buf][2048 + wid * 512]);
    gl_lds16(Bg + k0, &Bs[buf][wid * 512]);
    gl_lds16(Bg + (size_t)64 * K + k0, &Bs[buf][2048 + wid * 512]);
  };
  f32x4 acc[4][4] = {};
  int r16 = lane & 15, g = lane >> 4;
  int fslot = (g ^ (r16 & 3)) * 8;
  stage(0, 0);
  int cur = 0;
  for (int ks = 0; ks < nk; ks++) {
    __syncthreads();
    if (ks + 1 < nk) stage(cur ^ 1, ks + 1);
    bf16x8 af[4], bfr[4];
#pragma unroll
    for (int m = 0; m < 4; m++)
      af[m] = *(const bf16x8*)&As[cur][(wr * 64 + m * 16 + r16) * 32 + fslot];
#pragma unroll
    for (int n = 0; n < 4; n++)
      bfr[n] = *(const bf16x8*)&Bs[cur][(wc * 64 + n * 16 + r16) * 32 + fslot];
#pragma unroll
    for (int m = 0; m < 4; m++)
#pragma unroll
      for (int n = 0; n < 4; n++)
        acc[m][n] = mfma16(af[m], bfr[n], acc[m][n]);
    cur ^= 1;
  }
  int col = lane & 15, rb = (lane >> 4) * 4;
  const float* bias = strm ? bias1 : bias0;
  float* part = MODE == 4 ? (float*)out0 + (size_t)blockIdx.z * LQ * N : nullptr;
#pragma unroll
  for (int m = 0; m < 4; m++) {
#pragma unroll
    for (int n = 0; n < 4; n++) {
      int gn = bn * 128 + wc * 64 + n * 16 + col;
      float bv = MODE == 4 ? 0.f : bias[gn];
#pragma unroll
      for (int r = 0; r < 4; r++) {
        int lr = wr * 64 + m * 16 + rb + r;
        float v = acc[m][n][r] + bv;
        if (MODE == 0) {
          ((bf16*)(strm ? out1 : out0))[(size_t)(lm + lr) * N + gn] = (bf16)v;
        } else if (MODE == 2) {
          // gelu_tanh == v * sigmoid(2u), u = 0.79788456*(v + 0.044715 v^3)
          float u2 = 1.5957691216057308f * (v + 0.044715f * v * v * v);
          float ge = v / (1.f + __expf(-u2));
          ((bf16*)(strm ? out1 : out0))[(size_t)(lm + lr) * N + gn] = (bf16)ge;
        } else {
          part[(size_t)(bm * 128 + lr) * N + gn] = v;
        }
      }
    }
  }
}

// ---------------- split-K combine: out = res + gate*(sum(part)+bias), f32 ----------------
template <int S>
__global__ __launch_bounds__(256) void k_skcomb(
    const float* __restrict__ part, int N,
    const float* __restrict__ bias0, const float* __restrict__ bias1,
    const float* __restrict__ gate0, const float* __restrict__ gate1,
    const float* __restrict__ res0, const float* __restrict__ res1,
    float* __restrict__ out0, float* __restrict__ out1) {
  int gid = blockIdx.x * 256 + threadIdx.x;
  int nv = N >> 2;
  int row = gid / nv, cv = gid - row * nv;
  int strm = row >= LT;
  int lrow = row - strm * LT;
  const float* bias = strm ? bias1 : bias0;
  const float* gate = strm ? gate1 : gate0;
  const float* res = strm ? res1 : res0;
  float* out = strm ? out1 : out0;
  int c = cv * 4;
  float4 acc = *(const float4*)(bias + c);
#pragma unroll
  for (int s = 0; s < S; s++) {
    float4 p = *(const float4*)(part + ((size_t)s * LQ + row) * N + c);
    acc.x += p.x; acc.y += p.y; acc.z += p.z; acc.w += p.w;
  }
  float4 g = *(const float4*)(gate + c);
  float4 r = *(const float4*)(res + (size_t)lrow * N + c);
  float4 o = {r.x + g.x * acc.x, r.y + g.y * acc.y, r.z + g.z * acc.z, r.w + g.w * acc.w};
  *(float4*)(out + (size_t)lrow * N + c) = o;
}

// ---------------- qkv post: RMS norm (q,k) + RoPE + scale ----------------
__global__ __launch_bounds__(256) void k_qkv_post(
    const bf16* __restrict__ y, const float* __restrict__ pe,
    const float* __restrict__ qn0, const float* __restrict__ kn0,
    const float* __restrict__ qn1, const float* __restrict__ kn1,
    bf16* __restrict__ qh, bf16* __restrict__ kh) {
  int wv = (int)((blockIdx.x * 256 + threadIdx.x) >> 6);
  int lane = threadIdx.x & 63;
  int head = wv / LQ, l = wv - head * LQ;
  const bf16* yr = y + (size_t)l * (3 * HS) + head * HD;
  float q0 = (float)yr[2 * lane], q1 = (float)yr[2 * lane + 1];
  float k0 = (float)yr[HS + 2 * lane], k1 = (float)yr[HS + 2 * lane + 1];
  float sqs = q0 * q0 + q1 * q1, sks = k0 * k0 + k1 * k1;
#pragma unroll
  for (int m = 1; m < 64; m <<= 1) { sqs += __shfl_xor(sqs, m); sks += __shfl_xor(sks, m); }
  float rq = rsqrtf(sqs * (1.f / HD) + 1e-6f);
  float rk = rsqrtf(sks * (1.f / HD) + 1e-6f);
  int strm = l >= LT;
  const float* qn = strm ? qn1 : qn0;
  const float* kn = strm ? kn1 : kn0;
  float e0 = q0 * rq * qn[2 * lane], e1 = q1 * rq * qn[2 * lane + 1];
  float f0 = k0 * rk * kn[2 * lane], f1 = k1 * rk * kn[2 * lane + 1];
  float4 p = *(const float4*)(pe + ((size_t)l * 64 + lane) * 4);
  // 128^-0.5 * log2(e) folded into q: softmax runs in exp2 domain
  const float scl = 0.12751744f;
  size_t qi = ((size_t)head * LQ + l) * HD + 2 * lane;
  bf16x2 qv = {(bf16)((p.x * e0 + p.y * e1) * scl), (bf16)((p.z * e0 + p.w * e1) * scl)};
  bf16x2 kv = {(bf16)(p.x * f0 + p.y * f1), (bf16)(p.z * f0 + p.w * f1)};
  *(bf16x2*)(qh + qi) = qv;
  *(bf16x2*)(kh + qi) = kv;
}

// ---------------- V transpose: y v-part [l][head*HD+d] -> vT [head][d][l] ----------------
__global__ __launch_bounds__(256) void k_vtrans(const bf16* __restrict__ y,
                                                bf16* __restrict__ vT) {
  __shared__ bf16 t[32][34];
  int head = blockIdx.y >> 2, dt = blockIdx.y & 3;
  int tx = threadIdx.x & 31, ty = threadIdx.x >> 5;
  int l0 = blockIdx.x * 32, d0 = dt * 32;
  for (int i = 0; i < 32; i += 8)
    t[ty + i][tx] = y[(size_t)(l0 + ty + i) * (3 * HS) + 2 * HS + head * HD + d0 + tx];
  __syncthreads();
  for (int i = 0; i < 32; i += 8)
    vT[(size_t)(head * HD + d0 + ty + i) * LQ + l0 + tx] = t[tx][ty + i];
}

// ---------------- flash attention: KV-split x4, dbuf LDS, swapped-QK in-register softmax ----
// S = mfma(K, Q) -> D[kv][q]: lane holds 8 kv scores for ONE q col (r16); softmax is
// in-lane + 2 shfl. P rearranged to PV B-frag via 8 shfl (no P LDS). O^T = mfma(V^T, P).
__global__ __launch_bounds__(256, 5) void k_attn(
    const bf16* __restrict__ Q, const bf16* __restrict__ Kh,
    const bf16* __restrict__ VT, bf16* __restrict__ Op, float* __restrict__ ml) {
  __shared__ bf16 Ks[2][KVBLK * 128];
  __shared__ bf16 Vs[2][128 * KVBLK];
  int tid = threadIdx.x, lane = tid & 63, w = tid >> 6;
  int b = blockIdx.x;
  int qb = b % 40;
  int split = (b / 40) % SPLIT;
  int head = b / (40 * SPLIT);
  int qr = qb * 64 + w * 16;
  int r16 = lane & 15, g = lane >> 4;
  const bf16* qp = Q + ((size_t)head * LQ + qr + r16) * HD + g * 8;
  bf16x8 qf[4];
#pragma unroll
  for (int c = 0; c < 4; c++) qf[c] = *(const bf16x8*)(qp + c * 32);
  f32x4 O[8] = {};
  float mr = -1e30f, lr = 0.f;  // running max/sum for q col r16 (dup across g)
  const bf16* kbase = Kh + ((size_t)head * LQ + split * KVS) * HD;
  const bf16* vbase = VT + (size_t)head * HD * LQ + split * KVS;
  int krow0 = w * 8 + (lane >> 4);
  int kslot = lane & 15;
  int vrow0 = w * 32 + (lane >> 2);
  int vslot = lane & 3;
  auto stage = [&](int buf, int t) {
    int kv0 = t * KVBLK;
#pragma unroll
    for (int i = 0; i < 2; i++) {
      int krow = krow0 + i * 4;
      gl_lds16(kbase + (size_t)(kv0 + krow) * HD + ((kslot ^ (krow & 7)) << 3),
               &Ks[buf][(w * 8 + i * 4) * 128]);
      int vrow = vrow0 + i * 16;
      gl_lds16(vbase + (size_t)vrow * LQ + kv0 + ((vslot ^ (vrow & 3)) << 3),
               &Vs[buf][(w * 32 + i * 16) * KVBLK]);
    }
  };
  stage(0, 0);
  int cur = 0;
  int src0 = r16 + ((g & 1) << 5);  // source lane for P-frag lo half
  bool hiS = g >= 2;                // this lane's kv range lives in S1
  for (int t = 0; t < NTILES; t++) {
    __syncthreads();
    if (t + 1 < NTILES) stage(cur ^ 1, t + 1);
    const bf16* ks = &Ks[cur][0];
    const bf16* vs = &Vs[cur][0];
    // S = K·Q^T (swapped): rows kv, cols q
    f32x4 S0 = {}, S1 = {};
    int sw = (r16 & 7);
#pragma unroll
    for (int c = 0; c < 4; c++) {
      int slot = ((4 * c + g) ^ sw) << 3;
      bf16x8 ka = *(const bf16x8*)&ks[r16 * 128 + slot];
      bf16x8 kb = *(const bf16x8*)&ks[(16 + r16) * 128 + slot];
      S0 = mfma16(ka, qf[c], S0);
      S1 = mfma16(kb, qf[c], S1);
    }
    // tile max over 32 kv for this q col: 7 in-lane + 2 shfl
    float mx = fmaxf(fmaxf(fmaxf(S0[0], S0[1]), fmaxf(S0[2], S0[3])),
                     fmaxf(fmaxf(S1[0], S1[1]), fmaxf(S1[2], S1[3])));
    mx = fmaxf(mx, __shfl_xor(mx, 16));
    mx = fmaxf(mx, __shfl_xor(mx, 32));
    bool keep = __all(mx <= mr + 8.f);  // defer-max (T13), log2 domain
    float alpha = 1.f;
    if (!keep) {
      float mn = fmaxf(mr, mx);
      alpha = exp2f(mr - mn);
      mr = mn;
    }
    float p0 = exp2f(S0[0] - mr), p1 = exp2f(S0[1] - mr);
    float p2 = exp2f(S0[2] - mr), p3 = exp2f(S0[3] - mr);
    float p4 = exp2f(S1[0] - mr), p5 = exp2f(S1[1] - mr);
    float p6 = exp2f(S1[2] - mr), p7 = exp2f(S1[3] - mr);
    float rs = ((p0 + p1) + (p2 + p3)) + ((p4 + p5) + (p6 + p7));
    rs += __shfl_xor(rs, 16);
    rs += __shfl_xor(rs, 32);
    lr = fmaf(lr, alpha, rs);
    // pack P to bf16 pairs (kv-consecutive), rearrange to PV B-frag via shfl
    bf16x2 a0 = {(bf16)p0, (bf16)p1}, a1 = {(bf16)p2, (bf16)p3};
    bf16x2 b0 = {(bf16)p4, (bf16)p5}, b1 = {(bf16)p6, (bf16)p7};
    int A0 = *(int*)&a0, A1 = *(int*)&a1, B0 = *(int*)&b0, B1 = *(int*)&b1;
    int x0a = __shfl(A0, src0), x0b = __shfl(B0, src0);
    int x1a = __shfl(A1, src0), x1b = __shfl(B1, src0);
    int x2a = __shfl(A0, src0 + 16), x2b = __shfl(B0, src0 + 16);
    int x3a = __shfl(A1, src0 + 16), x3b = __shfl(B1, src0 + 16);
    union { int u[4]; bf16x8 v; } pu;
    pu.u[0] = hiS ? x0b : x0a;
    pu.u[1] = hiS ? x1b : x1a;
    pu.u[2] = hiS ? x2b : x2a;
    pu.u[3] = hiS ? x3b : x3a;
    bf16x8 pf = pu.v;
    if (!keep) {
#pragma unroll
      for (int n = 0; n < 8; n++) O[n] *= alpha;
    }
    int vsl = (g ^ (r16 & 3)) * 8;
#pragma unroll
    for (int n = 0; n < 8; n++) {
      bf16x8 vf = *(const bf16x8*)&vs[(n * 16 + r16) * KVBLK + vsl];
      O[n] = mfma16(vf, pf, O[n]);  // O^T: rows d, col q
    }
    cur ^= 1;
  }
  const int NL = NH * LQ;
  bf16* op = Op + (size_t)split * NL * HD;
  size_t rowbase = ((size_t)head * LQ + qr + r16) * HD + 4 * g;
#pragma unroll
  for (int n = 0; n < 8; n++) {
    bf16x4 ov = {(bf16)O[n][0], (bf16)O[n][1], (bf16)O[n][2], (bf16)O[n][3]};
    *(bf16x4*)(op + rowbase + n * 16) = ov;
  }
  if (g == 0) {
    int idx = head * LQ + qr + r16;
    ml[(size_t)(split * 2 + 0) * NL + idx] = mr;
    ml[(size_t)(split * 2 + 1) * NL + idx] = lr;
  }
}

// ---------------- combine SPLIT KV-parts -> attnb [l][head*HD+d] bf16 ----------------
__global__ __launch_bounds__(256) void k_attn_combine(
    const bf16* __restrict__ Op, const float* __restrict__ ml, bf16* __restrict__ out) {
  int lane = threadIdx.x & 63, w = threadIdx.x >> 6;
  int row = blockIdx.x * 4 + w;  // head*LQ + l
  int head = row / LQ, l = row - head * LQ;
  const int NL = NH * LQ;
  float ms[SPLIT], ls[SPLIT], m = -1e30f;
#pragma unroll
  for (int s = 0; s < SPLIT; s++) {
    ms[s] = ml[(size_t)(s * 2) * NL + row];
    ls[s] = ml[(size_t)(s * 2 + 1) * NL + row];
    m = fmaxf(m, ms[s]);
  }
  float wsum = 0.f, wgt[SPLIT];
#pragma unroll
  for (int s = 0; s < SPLIT; s++) { wgt[s] = exp2f(ms[s] - m); wsum += wgt[s] * ls[s]; }
  float inv = 1.f / wsum;
  size_t oi = (size_t)row * HD + 2 * lane;
  float a0 = 0.f, a1 = 0.f;
#pragma unroll
  for (int s = 0; s < SPLIT; s++) {
    bf16x2 v = *(const bf16x2*)(Op + (size_t)s * NL * HD + oi);
    a0 += wgt[s] * (float)v[0];
    a1 += wgt[s] * (float)v[1];
  }
  bf16x2 ov = {(bf16)(a0 * inv), (bf16)(a1 * inv)};
  *(bf16x2*)(out + (size_t)l * HS + head * HD + 2 * lane) = ov;
}

// ---------------- launch ----------------
extern "C" void kernel_launch(void* const* d_in, const int* in_sizes, int n_in,
                              void* d_out, int out_size, void* d_ws, size_t ws_size,
                              hipStream_t stream) {
  const float* img = (const float*)d_in[0];
  const float* txt = (const float*)d_in[1];
  const float* vec = (const float*)d_in[2];
  const float* pe = (const float*)d_in[3];
#define PARAM(i) ((const float*)d_in[i])

  char* ws = (char*)d_ws;
  size_t off = 0;
  auto alloc = [&](size_t b) { void* p = ws + off; off += (b + 255) & ~(size_t)255; return p; };
  float* silu_s = (float*)alloc((size_t)HS * 4);
  float* mpart = (float*)alloc((size_t)8 * 2 * 12288 * 4);
  float* mod = (float*)alloc((size_t)2 * 6 * HS * 4);
  bf16* qkvT0 = (bf16*)alloc((size_t)3 * HS * HS * 2);
  bf16* qkvT1 = (bf16*)alloc((size_t)3 * HS * HS * 2);
  bf16* projT0 = (bf16*)alloc((size_t)HS * HS * 2);
  bf16* projT1 = (bf16*)alloc((size_t)HS * HS * 2);
  bf16* mlp1T0 = (bf16*)alloc((size_t)MLP_D * HS * 2);
  bf16* mlp1T1 = (bf16*)alloc((size_t)MLP_D * HS * 2);
  bf16* mlp2T0 = (bf16*)alloc((size_t)HS * MLP_D * 2);
  bf16* mlp2T1 = (bf16*)alloc((size_t)HS * MLP_D * 2);
  bf16* xm = (bf16*)alloc((size_t)LQ * HS * 2);
  bf16* y = (bf16*)alloc((size_t)LQ * 3 * HS * 2);
  bf16* qh = (bf16*)alloc((size_t)NH * LQ * HD * 2);
  bf16* kh = (bf16*)alloc((size_t)NH * LQ * HD * 2);
  bf16* vT = (bf16*)alloc((size_t)NH * HD * LQ * 2);
  bf16* attnb = (bf16*)alloc((size_t)LQ * HS * 2);
  float* x2 = (float*)alloc((size_t)LQ * HS * 4);
  bf16* xm2 = (bf16*)alloc((size_t)LQ * HS * 2);
  bf16* h = (bf16*)alloc((size_t)LQ * MLP_D * 2);
  float* ml = (float*)alloc((size_t)2 * SPLIT * NH * LQ * 4);
  bf16* Op = h;                 // attn partials alias h (dead until step 9)
  float* skpart = (float*)xm;   // split-K partials alias xm.. (dead regions)
  (void)ws_size; (void)in_sizes; (void)n_in; (void)out_size;

  const float* t_mod = mod;
  const float* i_mod = mod + 6 * HS;

  // 1) modulation vectors
  k_silu<<<HS / 256, 256, 0, stream>>>(vec, silu_s);
  k_mod_partial<<<dim3(96, 8), 256, 0, stream>>>(silu_s, PARAM(20), PARAM(4), mpart);
  k_mod_reduce<<<96, 256, 0, stream>>>(mpart, PARAM(21), PARAM(5), mod);

  // 2) weight transpose+cvt (64x64 tiles)
  k_transpose_cvt<<<dim3(3 * HS / 64, HS / 64), 256, 0, stream>>>(PARAM(24), qkvT0, HS, 3 * HS);
  k_transpose_cvt<<<dim3(3 * HS / 64, HS / 64), 256, 0, stream>>>(PARAM(8), qkvT1, HS, 3 * HS);
  k_transpose_cvt<<<dim3(HS / 64, HS / 64), 256, 0, stream>>>(PARAM(28), projT0, HS, HS);
  k_transpose_cvt<<<dim3(HS / 64, HS / 64), 256, 0, stream>>>(PARAM(12), projT1, HS, HS);
  k_transpose_cvt<<<dim3(MLP_D / 64, HS / 64), 256, 0, stream>>>(PARAM(32), mlp1T0, HS, MLP_D);
  k_transpose_cvt<<<dim3(MLP_D / 64, HS / 64), 256, 0, stream>>>(PARAM(16), mlp1T1, HS, MLP_D);
  k_transpose_cvt<<<dim3(HS / 64, MLP_D / 64), 256, 0, stream>>>(PARAM(34), mlp2T0, MLP_D, HS);
  k_transpose_cvt<<<dim3(HS / 64, MLP_D / 64), 256, 0, stream>>>(PARAM(18), mlp2T1, MLP_D, HS);

  // 3) LN1 + modulate
  k_ln_mod<<<LQ, 256, 0, stream>>>(txt, img, PARAM(22), PARAM(23), PARAM(6), PARAM(7),
                                   t_mod, i_mod, 0, 1, xm);

  // 4) qkv GEMM
  k_gemm<0><<<dim3(3 * HS / 128, LQ / 128), 256, 0, stream>>>(
      xm, HS, 3 * HS, HS, qkvT0, qkvT1, PARAM(25), PARAM(9), y, y + (size_t)LT * 3 * HS);

  // 5) RMS + RoPE ; V transpose
  k_qkv_post<<<NH * LQ / 4, 256, 0, stream>>>(y, pe, PARAM(26), PARAM(27), PARAM(10), PARAM(11),
                                              qh, kh);
  k_vtrans<<<dim3(LQ / 32, NH * 4), 256, 0, stream>>>(y, vT);

  // 6) attention (KV-split x4, swapped-QK in-reg softmax) + combine
  k_attn<<<NH * SPLIT * 40, 256, 0, stream>>>(qh, kh, vT, Op, ml);
  k_attn_combine<<<NH * LQ / 4, 256, 0, stream>>>(Op, ml, attnb);

  // 7) proj GEMM split-K x2 + combine -> x2
  k_gemm<4><<<dim3(HS / 128, LQ / 128, 2), 256, 0, stream>>>(
      attnb, HS, HS, HS / 2, projT0, projT1, nullptr, nullptr, skpart, nullptr);
  k_skcomb<2><<<LQ * HS / 4 / 256, 256, 0, stream>>>(
      skpart, HS, PARAM(29), PARAM(13), t_mod + 2 * HS, i_mod + 2 * HS, txt, img,
      x2, x2 + (size_t)LT * HS);

  // 8) LN2 + modulate
  k_ln_mod<<<LQ, 256, 0, stream>>>(x2, x2 + (size_t)LT * HS, PARAM(30), PARAM(31), PARAM(14),
                                   PARAM(15), t_mod, i_mod, 3, 4, xm2);

  // 9) MLP1 + gelu
  k_gemm<2><<<dim3(MLP_D / 128, LQ / 128), 256, 0, stream>>>(
      xm2, HS, MLP_D, HS, mlp1T0, mlp1T1, PARAM(33), PARAM(17), h, h + (size_t)LT * MLP_D);

  // 10) MLP2 split-K x4 + combine -> d_out (img first)
  float* out_img = (float*)d_out;
  float* out_txt = (float*)d_out + (size_t)LI * HS;
  k_gemm<4><<<dim3(HS / 128, LQ / 128, 4), 256, 0, stream>>>(
      h, MLP_D, HS, MLP_D / 4, mlp2T0, mlp2T1, nullptr, nullptr, skpart, nullptr);
  k_skcomb<4><<<LQ * HS / 4 / 256, 256, 0, stream>>>(
      skpart, HS, PARAM(35), PARAM(19), t_mod + 5 * HS, i_mod + 5 * HS, x2,
      x2 + (size_t)LT * HS, out_txt, out_img);
}